// Round 2
// baseline (2999.939 us; speedup 1.0000x reference)
//
#include <hip/hip_runtime.h>

#define DEVI __device__ __forceinline__

// ---------------- vector LDS/global load helper (aligned) ----------------
template<int N>
DEVI void ldvec(float* dst, const float* src) {
  #pragma unroll
  for (int i = 0; i + 4 <= N; i += 4)
    *reinterpret_cast<float4*>(dst + i) = *reinterpret_cast<const float4*>(src + i);
  if constexpr ((N & 3) >= 2)
    *reinterpret_cast<float2*>(dst + (N & ~3)) = *reinterpret_cast<const float2*>(src + (N & ~3));
  if constexpr ((N & 3) == 1 || (N & 3) == 3)
    dst[N - 1] = src[N - 1];
}

// ---------------- weight transpose: wt[ci][co][k] = w[co][ci][k] ----------------
__global__ void transpose_w(const float* __restrict__ w, float* __restrict__ wt,
                            int Cout, int Cin, int K) {
  int i = blockIdx.x * 256 + threadIdx.x;
  int total = Cout * Cin * K;
  if (i >= total) return;
  int k = i % K;
  int ci = (i / K) % Cin;
  int co = i / (K * Cin);
  wt[((size_t)ci * Cout + co) * K + k] = w[i];
}

// ---------------- fused enc1+enc2 ----------------
// enc1: 1->64, k4 s2 p1 circular, relu (computed in staging)
// enc2: 64->128, k4 s2 p1 circular, relu. out (B,128,1024)
__global__ __launch_bounds__(256)
void enc12_kernel(const float* __restrict__ x, const float* __restrict__ w1,
                  const float* __restrict__ b1, const float* __restrict__ wt2,
                  const float* __restrict__ b2, float* __restrict__ out) {
  constexpr int SPAN = 66, SPANP = 68;
  __shared__ float xs[64][SPANP];
  __shared__ float wsm[16][512];
  const int n = blockIdx.x >> 5;
  const int t0 = (blockIdx.x & 31) << 5;   // 32 outputs per tile, Tout=1024
  const int tid = threadIdx.x;
  const int lo = 2 * t0 - 1;               // enc1-out coords, circular mod 2048
  const float* xb = x + (size_t)n * 4096;

  for (int l = tid; l < 64 * SPAN; l += 256) {
    int ci = l / SPAN, j = l - ci * SPAN;
    int t1 = (lo + j + 2048) & 2047;
    int p = 2 * t1 - 1;                    // x coords, circular mod 4096
    float4 wv = *reinterpret_cast<const float4*>(w1 + ci * 4);
    float s = b1[ci];
    s = fmaf(wv.x, xb[(p + 4096) & 4095], s);
    s = fmaf(wv.y, xb[(p + 4097) & 4095], s);
    s = fmaf(wv.z, xb[(p + 4098) & 4095], s);
    s = fmaf(wv.w, xb[(p + 4099) & 4095], s);
    xs[ci][j] = fmaxf(s, 0.0f);
  }

  const int cg = tid >> 3;        // 32 co-groups
  const int tg = tid & 7;         // 8 t-groups * 4 outputs
  const int co0 = cg * 4;
  float acc[4][4] = {};
  for (int c0 = 0; c0 < 64; c0 += 16) {
    __syncthreads();
    for (int l = tid; l < 16 * 512; l += 256)
      (&wsm[0][0])[l] = wt2[(size_t)c0 * 512 + l];
    __syncthreads();
    #pragma unroll
    for (int cl = 0; cl < 16; ++cl) {
      float xv[10];
      ldvec<10>(xv, &xs[c0 + cl][8 * tg]);
      float wv[16];
      ldvec<16>(wv, &wsm[cl][co0 * 4]);
      #pragma unroll
      for (int c = 0; c < 4; ++c)
        #pragma unroll
        for (int j = 0; j < 4; ++j)
          #pragma unroll
          for (int kk = 0; kk < 4; ++kk)
            acc[c][j] = fmaf(wv[c * 4 + kk], xv[2 * j + kk], acc[c][j]);
    }
  }
  for (int c = 0; c < 4; ++c) {
    const int co = co0 + c;
    const float bv = b2[co];
    #pragma unroll
    for (int j = 0; j < 4; ++j) {
      const int t = t0 + tg * 4 + j;
      out[((size_t)n * 128 + co) * 1024 + t] = fmaxf(acc[c][j] + bv, 0.0f);
    }
  }
}

// ---------------- generic tiled conv (pad=1 if K>1, else pad=0) ----------------
// weights pre-transposed: wt[ci][co][k]
template<int CIN, int COUT, int K, int STRIDE, bool CIRC, bool TRANSOUT>
__global__ __launch_bounds__(256)
void conv_tiled(const float* __restrict__ in, const float* __restrict__ wt,
                const float* __restrict__ bias, const float* __restrict__ resid,
                float* __restrict__ out, int Tin, int in_relu, int out_relu) {
  constexpr int COG = COUT / 4;
  constexpr int TG = 256 / COG;
  constexpr int TT = TG * 4;
  constexpr int PAD = (K > 1) ? 1 : 0;
  constexpr int SPAN = STRIDE * (TT - 1) + K;
  constexpr int SPANP = (SPAN + 3) & ~3;
  constexpr int CICH = 16;
  constexpr int XN = STRIDE * 3 + K;
  static_assert(CIN % CICH == 0, "CIN must be multiple of CICH");
  __shared__ float xs[CIN][SPANP];
  __shared__ float wsm[CICH][COUT * K];

  const int Tout = Tin / STRIDE;
  const int tilesPerB = Tout / TT;
  const int n = blockIdx.x / tilesPerB;
  const int t0 = (blockIdx.x % tilesPerB) * TT;
  const int tid = threadIdx.x;
  const int lo = STRIDE * t0 - PAD;

  const float* inb = in + (size_t)n * CIN * Tin;
  for (int l = tid; l < CIN * SPAN; l += 256) {
    int ci = l / SPAN, j = l - ci * SPAN;
    int p = lo + j;
    float v;
    if (CIRC) {
      p = (p < 0) ? (p + Tin) : (p >= Tin ? p - Tin : p);
      v = inb[ci * Tin + p];
    } else {
      v = (p >= 0 && p < Tin) ? inb[ci * Tin + p] : 0.0f;
    }
    if (in_relu) v = fmaxf(v, 0.0f);
    xs[ci][j] = v;
  }

  const int cg = tid / TG;
  const int tg = tid - cg * TG;
  const int co0 = cg * 4;
  float acc[4][4] = {};

  for (int c0 = 0; c0 < CIN; c0 += CICH) {
    __syncthreads();
    for (int l = tid; l < CICH * COUT * K; l += 256)
      (&wsm[0][0])[l] = wt[(size_t)c0 * COUT * K + l];
    __syncthreads();
    #pragma unroll
    for (int cl = 0; cl < CICH; ++cl) {
      float xv[XN];
      ldvec<XN>(xv, &xs[c0 + cl][STRIDE * 4 * tg]);
      float wv[4 * K];
      ldvec<4 * K>(wv, &wsm[cl][co0 * K]);
      #pragma unroll
      for (int c = 0; c < 4; ++c)
        #pragma unroll
        for (int j = 0; j < 4; ++j)
          #pragma unroll
          for (int kk = 0; kk < K; ++kk)
            acc[c][j] = fmaf(wv[c * K + kk], xv[STRIDE * j + kk], acc[c][j]);
    }
  }

  for (int c = 0; c < 4; ++c) {
    const int co = co0 + c;
    const float bv = bias ? bias[co] : 0.0f;
    #pragma unroll
    for (int j = 0; j < 4; ++j) {
      const int t = t0 + tg * 4 + j;
      float v = acc[c][j] + bv;
      if (resid) v += resid[((size_t)n * COUT + co) * Tout + t];
      if (out_relu) v = fmaxf(v, 0.0f);
      if (TRANSOUT)
        out[((size_t)n * Tout + t) * COUT + co] = v;   // (BT, COUT) layout
      else
        out[((size_t)n * COUT + co) * Tout + t] = v;
    }
  }
}

// ---------------- transposed conv k=4 s=2 p=1 (zero boundary) ----------------
// weights in native layout w[ci][co][k]
template<int CIN, int COUT>
__global__ __launch_bounds__(256)
void convt_tiled(const float* __restrict__ in, const float* __restrict__ w,
                 const float* __restrict__ bias, float* __restrict__ out,
                 int Tin, int in_relu, int out_relu) {
  constexpr int COG = COUT / 4;
  constexpr int TG = 256 / COG;
  constexpr int OTT = TG * 8;
  constexpr int SPAN = OTT / 2 + 2;
  constexpr int SPANP = (SPAN + 3) & ~3;
  constexpr int CICH = 16;
  __shared__ float xs[CIN][SPANP];
  __shared__ float wsm[CICH][COUT * 4];
  const int Tout = 2 * Tin;
  const int tilesPerB = Tout / OTT;
  const int n = blockIdx.x / tilesPerB;
  const int ot0 = (blockIdx.x % tilesPerB) * OTT;
  const int itb = ot0 / 2 - 1;
  const int tid = threadIdx.x;
  const float* inb = in + (size_t)n * CIN * Tin;
  for (int l = tid; l < CIN * SPAN; l += 256) {
    int ci = l / SPAN, j = l - ci * SPAN;
    int p = itb + j;
    float v = (p >= 0 && p < Tin) ? inb[ci * Tin + p] : 0.0f;
    if (in_relu) v = fmaxf(v, 0.0f);
    xs[ci][j] = v;
  }
  const int cg = tid / TG;
  const int tg = tid - cg * TG;
  const int co0 = cg * 4;
  float acc[4][8] = {};
  for (int c0 = 0; c0 < CIN; c0 += CICH) {
    __syncthreads();
    for (int l = tid; l < CICH * COUT * 4; l += 256)
      (&wsm[0][0])[l] = w[(size_t)c0 * COUT * 4 + l];
    __syncthreads();
    #pragma unroll
    for (int cl = 0; cl < CICH; ++cl) {
      float xv[6];
      ldvec<6>(xv, &xs[c0 + cl][4 * tg]);
      float wv[16];
      ldvec<16>(wv, &wsm[cl][co0 * 4]);
      #pragma unroll
      for (int c = 0; c < 4; ++c) {
        #pragma unroll
        for (int j = 0; j < 8; j += 2) {
          acc[c][j]     = fmaf(wv[c * 4 + 3], xv[j / 2],
                          fmaf(wv[c * 4 + 1], xv[j / 2 + 1], acc[c][j]));
          acc[c][j + 1] = fmaf(wv[c * 4 + 2], xv[j / 2 + 1],
                          fmaf(wv[c * 4 + 0], xv[j / 2 + 2], acc[c][j + 1]));
        }
      }
    }
  }
  for (int c = 0; c < 4; ++c) {
    const int co = co0 + c;
    const float bv = bias[co];
    #pragma unroll
    for (int j = 0; j < 8; ++j) {
      const int ot = ot0 + tg * 8 + j;
      float v = acc[c][j] + bv;
      if (out_relu) v = fmaxf(v, 0.0f);
      out[((size_t)n * COUT + co) * Tout + ot] = v;
    }
  }
}

// ---------------- fused ct2 (128->64 convT, relu) + ct3 (64->1 convT) ----------------
// in: ct1 output (B,128,1024) already relu'd. out: x_recon (B,4096) at out3.
__global__ __launch_bounds__(256)
void ct23_kernel(const float* __restrict__ in, const float* __restrict__ w2,
                 const float* __restrict__ b2, const float* __restrict__ w3,
                 const float* __restrict__ b3, float* __restrict__ out3) {
  constexpr int CIN = 128, COUT = 64;
  constexpr int TG = 16, OTT = 128;          // ct2 outputs per block (all 64 ch)
  constexpr int SPAN = OTT / 2 + 2, SPANP = 68;
  constexpr int Tin = 1024, Tout = 2048;
  __shared__ float xs[CIN][SPANP];           // 34.8 KB; reused as ys after main loop
  __shared__ float wsm[16][COUT * 4];        // 16 KB
  float* ysb = &xs[0][0];                    // ys[64][132] = 8448 <= 128*68 = 8704

  const int tilesPerB = Tout / OTT;          // 16
  const int n = blockIdx.x / tilesPerB;
  const int ot0 = (blockIdx.x % tilesPerB) * OTT;
  const int itb = ot0 / 2 - 1;
  const int tid = threadIdx.x;
  const float* inb = in + (size_t)n * CIN * Tin;
  for (int l = tid; l < CIN * SPAN; l += 256) {
    int ci = l / SPAN, j = l - ci * SPAN;
    int p = itb + j;
    xs[ci][j] = (p >= 0 && p < Tin) ? inb[ci * Tin + p] : 0.0f;
  }
  const int cg = tid / TG;
  const int tg = tid - cg * TG;
  const int co0 = cg * 4;
  float acc[4][8] = {};
  float hl[4] = {}, hr[4] = {};
  for (int c0 = 0; c0 < CIN; c0 += 16) {
    __syncthreads();
    for (int l = tid; l < 16 * COUT * 4; l += 256)
      (&wsm[0][0])[l] = w2[(size_t)c0 * COUT * 4 + l];
    __syncthreads();
    #pragma unroll
    for (int cl = 0; cl < 16; ++cl) {
      float xv[6];
      ldvec<6>(xv, &xs[c0 + cl][4 * tg]);
      float wv[16];
      ldvec<16>(wv, &wsm[cl][co0 * 4]);
      #pragma unroll
      for (int c = 0; c < 4; ++c) {
        #pragma unroll
        for (int j = 0; j < 8; j += 2) {
          acc[c][j]     = fmaf(wv[c * 4 + 3], xv[j / 2],
                          fmaf(wv[c * 4 + 1], xv[j / 2 + 1], acc[c][j]));
          acc[c][j + 1] = fmaf(wv[c * 4 + 2], xv[j / 2 + 1],
                          fmaf(wv[c * 4 + 0], xv[j / 2 + 2], acc[c][j + 1]));
        }
      }
      if (tg == 0) {           // left halo ct2 output at ot0-1 (odd)
        #pragma unroll
        for (int c = 0; c < 4; ++c)
          hl[c] = fmaf(wv[c * 4 + 0], xv[1], fmaf(wv[c * 4 + 2], xv[0], hl[c]));
      }
      if (tg == TG - 1) {      // right halo ct2 output at ot0+OTT (even)
        #pragma unroll
        for (int c = 0; c < 4; ++c)
          hr[c] = fmaf(wv[c * 4 + 3], xv[4], fmaf(wv[c * 4 + 1], xv[5], hr[c]));
      }
    }
  }
  __syncthreads();   // xs reads complete before overwriting as ys
  for (int c = 0; c < 4; ++c) {
    const int co = co0 + c;
    const float bv = b2[co];
    #pragma unroll
    for (int j = 0; j < 8; ++j)
      ysb[co * 132 + 1 + tg * 8 + j] = fmaxf(acc[c][j] + bv, 0.0f);
    if (tg == 0)
      ysb[co * 132 + 0]       = (ot0 == 0) ? 0.0f : fmaxf(hl[c] + bv, 0.0f);
    if (tg == TG - 1)
      ysb[co * 132 + OTT + 1] = (ot0 + OTT == Tout) ? 0.0f : fmaxf(hr[c] + bv, 0.0f);
  }
  __syncthreads();
  // ct3: 256 outputs o3 = 2*ot0 + tid
  const int h = (tid + 1) >> 1;
  const int odd = tid & 1;
  const int ka = odd ? 0 : 1;
  const int kb = odd ? 2 : 3;
  float s = b3[0];
  #pragma unroll 8
  for (int ci = 0; ci < 64; ++ci) {
    s = fmaf(w3[ci * 4 + ka], ysb[ci * 132 + h + 1], s);
    s = fmaf(w3[ci * 4 + kb], ysb[ci * 132 + h], s);
  }
  out3[(size_t)n * 4096 + 2 * ot0 + tid] = s;
}

// ---------------- VQ ----------------
__global__ void ee_kernel(const float* __restrict__ emb, float* __restrict__ ee) {
  int c = blockIdx.x * 256 + threadIdx.x;
  if (c >= 512) return;
  float s = 0.0f;
  #pragma unroll
  for (int d = 0; d < 64; ++d) { float v = emb[c * 64 + d]; s = fmaf(v, v, s); }
  ee[c] = s;
}

__global__ __launch_bounds__(128)
void vq_argmin(const float* __restrict__ zt, const float* __restrict__ emb,
               const float* __restrict__ ee, int* __restrict__ idx,
               int* __restrict__ hist, float* __restrict__ loss_accum) {
  __shared__ float es[128 * 64];
  __shared__ float ees[128];
  __shared__ int lhist[512];
  __shared__ float lsum[2];
  const int tid = threadIdx.x;
  const int r = blockIdx.x * 128 + tid;
  float4 z[16];
  const float4* zr = reinterpret_cast<const float4*>(zt + (size_t)r * 64);
  float zz = 0.0f;
  #pragma unroll
  for (int i = 0; i < 16; ++i) {
    z[i] = zr[i];
    zz += z[i].x * z[i].x + z[i].y * z[i].y + z[i].z * z[i].z + z[i].w * z[i].w;
  }
  for (int l = tid; l < 512; l += 128) lhist[l] = 0;
  float best = 3.4e38f;
  int bi = 0;
  for (int c0 = 0; c0 < 512; c0 += 128) {
    __syncthreads();
    for (int l = tid; l < 128 * 64; l += 128) es[l] = emb[(size_t)c0 * 64 + l];
    if (tid < 128) ees[tid] = ee[c0 + tid];
    __syncthreads();
    for (int cc = 0; cc < 128; ++cc) {
      const float4* e4 = reinterpret_cast<const float4*>(es + cc * 64);
      float dot = 0.0f;
      #pragma unroll
      for (int i = 0; i < 16; ++i) {
        float4 e = e4[i];
        dot += z[i].x * e.x + z[i].y * e.y + z[i].z * e.z + z[i].w * e.w;
      }
      float d = ees[cc] - 2.0f * dot;   // zz omitted: constant per row
      if (d < best) { best = d; bi = c0 + cc; }
    }
  }
  idx[r] = bi;
  atomicAdd(&lhist[bi], 1);
  float v = zz + best;                  // == ||z - e_best||^2
  for (int off = 32; off > 0; off >>= 1) v += __shfl_down(v, off);
  if ((tid & 63) == 0) lsum[tid >> 6] = v;
  __syncthreads();
  if (tid == 0) atomicAdd(loss_accum, lsum[0] + lsum[1]);
  for (int l = tid; l < 512; l += 128)
    if (lhist[l]) atomicAdd(&hist[l], lhist[l]);
}

__global__ __launch_bounds__(256)
void gather_q(const int* __restrict__ idx, const float* __restrict__ emb,
              float* __restrict__ q) {
  // q (B,64,256)
  int o = blockIdx.x * 256 + threadIdx.x;
  int t = o & 255;
  int d = (o >> 8) & 63;
  int n = o >> 14;
  int id = idx[n * 256 + t];
  q[o] = emb[id * 64 + d];
}

__global__ __launch_bounds__(512)
void finalize(const int* __restrict__ hist, const float* __restrict__ loss_accum,
              float* __restrict__ out) {
  __shared__ float red[8];
  int tid = threadIdx.x;
  float avg = (float)hist[tid] * (1.0f / 65536.0f);
  float v = avg * logf(avg + 1e-10f);
  for (int off = 32; off > 0; off >>= 1) v += __shfl_down(v, off);
  if ((tid & 63) == 0) red[tid >> 6] = v;
  __syncthreads();
  if (tid == 0) {
    float s = 0.0f;
    for (int i = 0; i < 8; ++i) s += red[i];
    out[1048577] = expf(-s);
    out[0] = 1.25f * loss_accum[0] * (1.0f / (65536.0f * 64.0f));
  }
}

// ---------------- launcher ----------------
extern "C" void kernel_launch(void* const* d_in, const int* in_sizes, int n_in,
                              void* d_out, int out_size, void* d_ws, size_t ws_size,
                              hipStream_t stream) {
  (void)in_sizes; (void)n_in; (void)out_size; (void)ws_size;
  const float* x    = (const float*)d_in[0];
  const float* c1w  = (const float*)d_in[1];
  const float* c1b  = (const float*)d_in[2];
  const float* c2w  = (const float*)d_in[3];
  const float* c2b  = (const float*)d_in[4];
  const float* c3w  = (const float*)d_in[5];
  const float* c3b  = (const float*)d_in[6];
  const float* c4w  = (const float*)d_in[7];
  const float* c4b  = (const float*)d_in[8];
  const float* cfw  = (const float*)d_in[9];
  const float* cfb  = (const float*)d_in[10];
  const float* erw1 = (const float*)d_in[11];
  const float* erw2 = (const float*)d_in[12];
  const float* pqw  = (const float*)d_in[13];
  const float* pqb  = (const float*)d_in[14];
  const float* emb  = (const float*)d_in[15];
  const float* diw  = (const float*)d_in[16];
  const float* dib  = (const float*)d_in[17];
  const float* drw1 = (const float*)d_in[18];
  const float* drw2 = (const float*)d_in[19];
  const float* t0w  = (const float*)d_in[20];
  const float* t0b  = (const float*)d_in[21];
  const float* t1w  = (const float*)d_in[22];
  const float* t1b  = (const float*)d_in[23];
  const float* t2w  = (const float*)d_in[24];
  const float* t2b  = (const float*)d_in[25];
  const float* t3w  = (const float*)d_in[26];
  const float* t3b  = (const float*)d_in[27];

  float* ws = (float*)d_ws;
  // Big regions (aliased over time). Total ws use ~194 MiB.
  float* A  = ws;                         // 33,554,432 fl: enc2-out, later ct1-out
  float* Bb = ws + 33554432;              // 16,777,216 fl: enc3-out, later ct0-out
  // Smalls carved inside A (A's first value dead after enc3 reads it):
  float* C  = A;                          // 8,388,608 fl
  float* D  = A + 8388608;                // 8,388,608 fl
  float* hb = A + 16777216;               // 2,097,152 fl
  float* zt = A + 18874368;               // 4,194,304 fl (BT,64)
  float* qb = A + 23068672;               // 4,194,304 fl (B,64,256)
  // Weights/counters after B:
  float* wp    = ws + 50331648;
  float* w2t   = wp;            // 32768
  float* w3t   = wp + 32768;    // 65536
  float* w4t   = wp + 98304;    // 65536
  float* wcft  = wp + 163840;   // 49152
  float* wer1t = wp + 212992;   // 24576 (2 layers)
  float* wer2t = wp + 237568;   // 8192
  float* wpqt  = wp + 245760;   // 8192
  float* wdit  = wp + 253952;   // 24576
  float* wdr1t = wp + 278528;   // 24576
  float* wdr2t = wp + 303104;   // 8192
  float* eeb   = wp + 311296;   // 512
  int*   idxb  = (int*)(wp + 311808);   // 65536
  int*   histb = (int*)(wp + 377344);   // 512
  float* lossb = wp + 377856;           // 64
  float* outp  = (float*)d_out;

  hipMemsetAsync(histb, 0, 512 * sizeof(int), stream);
  hipMemsetAsync(lossb, 0, sizeof(float), stream);

  auto tw = [&](const float* w, float* dst, int Cout, int Cin, int K) {
    int total = Cout * Cin * K;
    transpose_w<<<(total + 255) / 256, 256, 0, stream>>>(w, dst, Cout, Cin, K);
  };
  tw(c2w, w2t, 128, 64, 4);
  tw(c3w, w3t, 128, 128, 4);
  tw(c4w, w4t, 128, 128, 4);
  tw(cfw, wcft, 128, 128, 3);
  tw(erw1, wer1t, 32, 128, 3);
  tw(erw1 + 12288, wer1t + 12288, 32, 128, 3);
  tw(erw2, wer2t, 128, 32, 1);
  tw(erw2 + 4096, wer2t + 4096, 128, 32, 1);
  tw(pqw, wpqt, 64, 128, 1);
  tw(diw, wdit, 128, 64, 3);
  tw(drw1, wdr1t, 32, 128, 3);
  tw(drw1 + 12288, wdr1t + 12288, 32, 128, 3);
  tw(drw2, wdr2t, 128, 32, 1);
  tw(drw2 + 4096, wdr2t + 4096, 128, 32, 1);
  ee_kernel<<<2, 256, 0, stream>>>(emb, eeb);

  // ---- encoder ----
  enc12_kernel<<<8192, 256, 0, stream>>>(x, c1w, c1b, w2t, c2b, A);
  conv_tiled<128, 128, 4, 2, true, false><<<4096, 256, 0, stream>>>(A, w3t, c3b, nullptr, Bb, 1024, 0, 1);
  conv_tiled<128, 128, 4, 2, true, false><<<2048, 256, 0, stream>>>(Bb, w4t, c4b, nullptr, C, 512, 0, 1);
  conv_tiled<128, 128, 3, 1, true, false><<<2048, 256, 0, stream>>>(C, wcft, cfb, nullptr, D, 256, 0, 0);
  // enc residual stack
  conv_tiled<128, 32, 3, 1, true, false><<<512, 256, 0, stream>>>(D, wer1t, nullptr, nullptr, hb, 256, 1, 0);
  conv_tiled<32, 128, 1, 1, false, false><<<2048, 256, 0, stream>>>(hb, wer2t, nullptr, D, C, 256, 1, 0);
  conv_tiled<128, 32, 3, 1, true, false><<<512, 256, 0, stream>>>(C, wer1t + 12288, nullptr, nullptr, hb, 256, 1, 0);
  conv_tiled<32, 128, 1, 1, false, false><<<2048, 256, 0, stream>>>(hb, wer2t + 4096, nullptr, C, D, 256, 1, 0);
  // prevq (res-stack final relu folded via in_relu), transposed (BT,64) output
  conv_tiled<128, 64, 1, 1, false, true><<<1024, 256, 0, stream>>>(D, wpqt, pqb, nullptr, zt, 256, 1, 0);
  // ---- VQ ----
  vq_argmin<<<512, 128, 0, stream>>>(zt, emb, eeb, idxb, histb, lossb);
  gather_q<<<16384, 256, 0, stream>>>(idxb, emb, qb);
  finalize<<<1, 512, 0, stream>>>(histb, lossb, outp);
  // ---- decoder ----
  conv_tiled<64, 128, 3, 1, false, false><<<2048, 256, 0, stream>>>(qb, wdit, dib, nullptr, C, 256, 0, 0);
  conv_tiled<128, 32, 3, 1, true, false><<<512, 256, 0, stream>>>(C, wdr1t, nullptr, nullptr, hb, 256, 1, 0);
  conv_tiled<32, 128, 1, 1, false, false><<<2048, 256, 0, stream>>>(hb, wdr2t, nullptr, C, D, 256, 1, 0);
  conv_tiled<128, 32, 3, 1, true, false><<<512, 256, 0, stream>>>(D, wdr1t + 12288, nullptr, nullptr, hb, 256, 1, 0);
  conv_tiled<32, 128, 1, 1, false, false><<<2048, 256, 0, stream>>>(hb, wdr2t + 4096, nullptr, D, C, 256, 1, 0);
  convt_tiled<128, 128><<<2048, 256, 0, stream>>>(C, t0w, t0b, Bb, 256, 1, 1);
  convt_tiled<128, 128><<<4096, 256, 0, stream>>>(Bb, t1w, t1b, A, 512, 0, 1);
  ct23_kernel<<<4096, 256, 0, stream>>>(A, t2w, t2b, t3w, t3b, outp + 1);
}

// Round 3
// 632.926 us; speedup vs baseline: 4.7398x; 4.7398x over previous
//
#include <hip/hip_runtime.h>

#define DEVI __device__ __forceinline__

typedef __bf16 bf16x8 __attribute__((ext_vector_type(8)));
typedef float f32x4 __attribute__((ext_vector_type(4)));

DEVI ushort f2b(float f) {            // f32 -> bf16 RNE
  uint b = __float_as_uint(f);
  uint r = (b + 0x7FFFu + ((b >> 16) & 1u)) >> 16;
  return (ushort)r;
}
DEVI float b2f(ushort u) { return __uint_as_float(((uint)u) << 16); }

// ======================= weight prep: all convs -> bf16 Wb[tap][co][ci] =======================
struct PrepArgs {
  int nw;
  int tot[20];
  const float* src[20];
  ushort* dst[20];
  int ci[20], co[20], sco[20], sci[20], sk[20];
};

__global__ __launch_bounds__(256)
void prep_all(PrepArgs a, int total) {
  int i = blockIdx.x * 256 + threadIdx.x;
  if (i >= total) return;
  int w = 0;
  while (i >= a.tot[w]) { i -= a.tot[w]; ++w; }
  const int li = i;
  const int CI = a.ci[w];
  int ciX = i % CI;
  int rest = i / CI;
  int coX = rest % a.co[w];
  int k = rest / a.co[w];
  a.dst[w][li] = f2b(a.src[w][coX * a.sco[w] + ciX * a.sci[w] + k * a.sk[w]]);
}

// ======================= enc1 scalar: x(f32,B,1,4096) -> (B,2048,64) bf16, relu ================
__global__ __launch_bounds__(256)
void enc1_bf(const float* __restrict__ x, const float* __restrict__ w1,
             const float* __restrict__ b1, ushort* __restrict__ out) {
  int i = blockIdx.x * 256 + threadIdx.x;    // (n,t): 256*2048
  int t = i & 2047, n = i >> 11;
  const float* xb = x + ((size_t)n << 12);
  int p = 2 * t - 1;
  float x0 = xb[(p + 4096) & 4095];
  float x1 = xb[(p + 4097) & 4095];
  float x2 = xb[(p + 4098) & 4095];
  float x3 = xb[(p + 4099) & 4095];
  uint ow[32];
  #pragma unroll
  for (int c2 = 0; c2 < 32; ++c2) {
    float4 wa = *reinterpret_cast<const float4*>(w1 + 8 * c2);
    float4 wb = *reinterpret_cast<const float4*>(w1 + 8 * c2 + 4);
    float s0 = fmaf(wa.x, x0, fmaf(wa.y, x1, fmaf(wa.z, x2, fmaf(wa.w, x3, b1[2 * c2]))));
    float s1 = fmaf(wb.x, x0, fmaf(wb.y, x1, fmaf(wb.z, x2, fmaf(wb.w, x3, b1[2 * c2 + 1]))));
    ow[c2] = (uint)f2b(fmaxf(s0, 0.0f)) | ((uint)f2b(fmaxf(s1, 0.0f)) << 16);
  }
  uint4* op = reinterpret_cast<uint4*>(out + ((size_t)i << 6));
  #pragma unroll
  for (int q = 0; q < 8; ++q)
    op[q] = uint4{ow[4 * q], ow[4 * q + 1], ow[4 * q + 2], ow[4 * q + 3]};
}

// ======================= MFMA forward conv =======================
// in (B,Tin,CI) bf16 -> out (B,Tout,CO) bf16.  Wb layout: [tap][co][ci] bf16.
// A = X (M=t, K=ci), B = W (K=ci, N=co). 16x16x32 bf16 MFMA.
template<int CI, int CO, int K, int S, bool CIRC>
__global__ __launch_bounds__(256)
void conv_mfma(const ushort* __restrict__ in, const ushort* __restrict__ wb,
               const float* __restrict__ bias, const ushort* __restrict__ resid,
               ushort* __restrict__ out, int Tin, int in_relu, int out_relu) {
  constexpr int PAD = (K > 1) ? 1 : 0;
  constexpr int NT = 4;                       // 4 t-tiles = 64 outputs / block
  constexpr int TT = NT * 16;
  constexpr int SPAN = S * (TT - 1) + K;
  constexpr int CIG = CI / 8;                 // 16B granules per row
  constexpr int COT = CO / 16;
  constexpr int WCOT = (COT + 3) / 4;         // co-tiles per wave: 128->2, 64->1, 32->1
  constexpr int WAVES_CO = COT / WCOT;        // 4,4,2
  constexpr int WAVES_T = 4 / WAVES_CO;       // 1,1,2
  constexpr int WTT = NT / WAVES_T;           // 4,4,2
  static_assert(CI % 32 == 0, "");

  __shared__ __align__(16) ushort xs[SPAN * CI];

  const int Tout = Tin / S;
  const int tilesPerB = Tout / TT;
  const int n = blockIdx.x / tilesPerB;
  const int t0 = (blockIdx.x % tilesPerB) * TT;
  const int tid = threadIdx.x;
  const int wid = tid >> 6, lane = tid & 63;
  const int l15 = lane & 15, l4 = lane >> 4;

  // ---- stage X tile: rows t_in0..t_in0+SPAN-1 into [t][ci] with granule swizzle ----
  const int t_in0 = S * t0 - PAD;
  const ushort* inb = in + (size_t)n * Tin * CI;
  for (int i = tid; i < SPAN * CIG; i += 256) {
    int t = i / CIG, g = i - (i / CIG) * CIG;
    int tg = t_in0 + t;
    uint4 v;
    if (CIRC) {
      tg = (tg < 0) ? tg + Tin : (tg >= Tin ? tg - Tin : tg);
      v = *reinterpret_cast<const uint4*>(inb + (size_t)tg * CI + g * 8);
    } else {
      if ((unsigned)tg < (unsigned)Tin)
        v = *reinterpret_cast<const uint4*>(inb + (size_t)tg * CI + g * 8);
      else
        v = uint4{0, 0, 0, 0};
    }
    if (in_relu) {
      ushort* pv = reinterpret_cast<ushort*>(&v);
      #pragma unroll
      for (int e = 0; e < 8; ++e) pv[e] = (pv[e] & 0x8000) ? 0 : pv[e];
    }
    *reinterpret_cast<uint4*>(&xs[t * CI + ((g ^ (t & (CIG - 1))) * 8)]) = v;
  }
  __syncthreads();

  const int wco = wid % WAVES_CO;
  const int wt = wid / WAVES_CO;
  const int co_base = wco * WCOT * 16;
  const int t_base = wt * WTT * 16;

  f32x4 acc[WTT][WCOT] = {};

  for (int cc = 0; cc < CI / 32; ++cc) {
    #pragma unroll
    for (int k = 0; k < K; ++k) {
      bf16x8 bfr[WCOT];
      #pragma unroll
      for (int c = 0; c < WCOT; ++c) {
        const ushort* wp = wb + (size_t)((k * CO + co_base + c * 16 + l15)) * CI + cc * 32 + l4 * 8;
        bfr[c] = __builtin_bit_cast(bf16x8, *reinterpret_cast<const uint4*>(wp));
      }
      #pragma unroll
      for (int tt2 = 0; tt2 < WTT; ++tt2) {
        int trow = S * (t_base + tt2 * 16 + l15) + k;
        int g = cc * 4 + l4;
        bf16x8 afr = __builtin_bit_cast(bf16x8, *reinterpret_cast<const uint4*>(
            &xs[trow * CI + ((g ^ (trow & (CIG - 1))) * 8)]));
        #pragma unroll
        for (int c = 0; c < WCOT; ++c)
          acc[tt2][c] = __builtin_amdgcn_mfma_f32_16x16x32_bf16(afr, bfr[c], acc[tt2][c], 0, 0, 0);
      }
    }
  }

  float bv[WCOT];
  #pragma unroll
  for (int c = 0; c < WCOT; ++c)
    bv[c] = bias ? bias[co_base + c * 16 + l15] : 0.0f;
  ushort* outb = out + (size_t)n * Tout * CO;
  const ushort* resb = resid ? resid + (size_t)n * Tout * CO : nullptr;
  #pragma unroll
  for (int tt2 = 0; tt2 < WTT; ++tt2)
    #pragma unroll
    for (int c = 0; c < WCOT; ++c)
      #pragma unroll
      for (int r = 0; r < 4; ++r) {
        int t = t0 + t_base + tt2 * 16 + 4 * l4 + r;
        int co = co_base + c * 16 + l15;
        float v = acc[tt2][c][r] + bv[c];
        if (resb) v += b2f(resb[(size_t)t * CO + co]);
        if (out_relu) v = fmaxf(v, 0.0f);
        outb[(size_t)t * CO + co] = f2b(v);
      }
}

// ======================= MFMA transposed conv k=4 s=2 p=1 (CI=128) =======================
// even ot=2t': taps w[k=1]@t', w[k=3]@t'-1 ; odd ot=2t'+1: w[k=0]@t'+1, w[k=2]@t'
template<int CO>
__global__ __launch_bounds__(256)
void convt_mfma(const ushort* __restrict__ in, const ushort* __restrict__ wb,
                const float* __restrict__ bias, ushort* __restrict__ out,
                int Tin, int in_relu, int out_relu) {
  constexpr int CI = 128, CIG = 16;
  constexpr int NT = 4, TT = 64;              // 64 t' -> 128 outputs / block
  constexpr int SPAN = TT + 2;
  constexpr int COT = CO / 16;
  constexpr int WCOT = (COT + 3) / 4;         // 128->2, 64->1
  constexpr int WAVES_CO = COT / WCOT;        // 4
  constexpr int WTT = NT;                     // 4 (WAVES_T = 1)

  __shared__ __align__(16) ushort xs[SPAN * CI];

  const int Tout = 2 * Tin;
  const int tilesPerB = Tin / TT;
  const int n = blockIdx.x / tilesPerB;
  const int tp0 = (blockIdx.x % tilesPerB) * TT;
  const int tid = threadIdx.x;
  const int wid = tid >> 6, lane = tid & 63;
  const int l15 = lane & 15, l4 = lane >> 4;

  const int t_in0 = tp0 - 1;
  const ushort* inb = in + (size_t)n * Tin * CI;
  for (int i = tid; i < SPAN * CIG; i += 256) {
    int t = i >> 4, g = i & 15;
    int tg = t_in0 + t;
    uint4 v;
    if ((unsigned)tg < (unsigned)Tin)
      v = *reinterpret_cast<const uint4*>(inb + (size_t)tg * CI + g * 8);
    else
      v = uint4{0, 0, 0, 0};
    if (in_relu) {
      ushort* pv = reinterpret_cast<ushort*>(&v);
      #pragma unroll
      for (int e = 0; e < 8; ++e) pv[e] = (pv[e] & 0x8000) ? 0 : pv[e];
    }
    *reinterpret_cast<uint4*>(&xs[t * CI + ((g ^ (t & 15)) * 8)]) = v;
  }
  __syncthreads();

  const int wco = wid % WAVES_CO;
  const int co_base = wco * WCOT * 16;

  f32x4 accE[WTT][WCOT] = {};
  f32x4 accO[WTT][WCOT] = {};

  auto lda = [&](int lt) -> bf16x8 {
    int g = 0;  // filled per call below
    (void)g;
    return bf16x8{};
  };
  (void)lda;

  for (int cc = 0; cc < 4; ++cc) {
    bf16x8 bk[4][WCOT];
    #pragma unroll
    for (int k = 0; k < 4; ++k)
      #pragma unroll
      for (int c = 0; c < WCOT; ++c) {
        const ushort* wp = wb + (size_t)((k * CO + co_base + c * 16 + l15)) * CI + cc * 32 + l4 * 8;
        bk[k][c] = __builtin_bit_cast(bf16x8, *reinterpret_cast<const uint4*>(wp));
      }
    #pragma unroll
    for (int tt2 = 0; tt2 < WTT; ++tt2) {
      int lt = tt2 * 16 + l15 + 1;            // local row of t' in xs
      int g = cc * 4 + l4;
      bf16x8 a0 = __builtin_bit_cast(bf16x8, *reinterpret_cast<const uint4*>(
          &xs[lt * CI + ((g ^ (lt & 15)) * 8)]));
      bf16x8 am = __builtin_bit_cast(bf16x8, *reinterpret_cast<const uint4*>(
          &xs[(lt - 1) * CI + ((g ^ ((lt - 1) & 15)) * 8)]));
      bf16x8 ap = __builtin_bit_cast(bf16x8, *reinterpret_cast<const uint4*>(
          &xs[(lt + 1) * CI + ((g ^ ((lt + 1) & 15)) * 8)]));
      #pragma unroll
      for (int c = 0; c < WCOT; ++c) {
        accE[tt2][c] = __builtin_amdgcn_mfma_f32_16x16x32_bf16(a0, bk[1][c], accE[tt2][c], 0, 0, 0);
        accE[tt2][c] = __builtin_amdgcn_mfma_f32_16x16x32_bf16(am, bk[3][c], accE[tt2][c], 0, 0, 0);
        accO[tt2][c] = __builtin_amdgcn_mfma_f32_16x16x32_bf16(ap, bk[0][c], accO[tt2][c], 0, 0, 0);
        accO[tt2][c] = __builtin_amdgcn_mfma_f32_16x16x32_bf16(a0, bk[2][c], accO[tt2][c], 0, 0, 0);
      }
    }
  }

  float bv[WCOT];
  #pragma unroll
  for (int c = 0; c < WCOT; ++c) bv[c] = bias[co_base + c * 16 + l15];
  ushort* outb = out + (size_t)n * Tout * CO;
  #pragma unroll
  for (int tt2 = 0; tt2 < WTT; ++tt2)
    #pragma unroll
    for (int c = 0; c < WCOT; ++c)
      #pragma unroll
      for (int r = 0; r < 4; ++r) {
        int tp = tp0 + tt2 * 16 + 4 * l4 + r;
        int co = co_base + c * 16 + l15;
        float vE = accE[tt2][c][r] + bv[c];
        float vO = accO[tt2][c][r] + bv[c];
        if (out_relu) { vE = fmaxf(vE, 0.0f); vO = fmaxf(vO, 0.0f); }
        outb[(size_t)(2 * tp) * CO + co] = f2b(vE);
        outb[(size_t)(2 * tp + 1) * CO + co] = f2b(vO);
      }
}

// ======================= ct3 scalar: (B,2048,64) bf16 -> (B,4096) f32 =======================
__global__ __launch_bounds__(256)
void ct3_bf(const ushort* __restrict__ in, const float* __restrict__ w3,
            const float* __restrict__ b3, float* __restrict__ out) {
  constexpr int SPAN = 130;
  __shared__ __align__(16) ushort ys[SPAN * 64];
  const int n = blockIdx.x >> 4;
  const int ot0 = (blockIdx.x & 15) << 8;   // 256 outputs / block
  const int tid = threadIdx.x;
  const int t_in0 = (ot0 >> 1) - 1;
  const ushort* inb = in + (size_t)n * 2048 * 64;
  for (int i = tid; i < SPAN * 8; i += 256) {
    int t = i >> 3, g = i & 7;
    int tg = t_in0 + t;
    uint4 v;
    if ((unsigned)tg < 2048u)
      v = *reinterpret_cast<const uint4*>(inb + (size_t)tg * 64 + g * 8);
    else
      v = uint4{0, 0, 0, 0};
    *reinterpret_cast<uint4*>(&ys[t * 64 + ((g ^ (t & 7)) * 8)]) = v;
  }
  __syncthreads();
  const int ot = ot0 + tid;
  const int odd = ot & 1;
  const int it_a = odd ? ((ot + 1) >> 1) : (ot >> 1);
  const int it_b = odd ? ((ot - 1) >> 1) : (ot / 2 - 1);
  const int ka = odd ? 0 : 1;
  const int kb = odd ? 2 : 3;
  const int lt_a = it_a - t_in0, lt_b = it_b - t_in0;
  float s = b3[0];
  #pragma unroll
  for (int g = 0; g < 8; ++g) {
    uint4 va = *reinterpret_cast<const uint4*>(&ys[lt_a * 64 + ((g ^ (lt_a & 7)) * 8)]);
    uint4 vb = *reinterpret_cast<const uint4*>(&ys[lt_b * 64 + ((g ^ (lt_b & 7)) * 8)]);
    const ushort* pa = reinterpret_cast<const ushort*>(&va);
    const ushort* pb = reinterpret_cast<const ushort*>(&vb);
    #pragma unroll
    for (int e = 0; e < 8; ++e) {
      int ci = g * 8 + e;
      s = fmaf(w3[ci * 4 + ka], b2f(pa[e]), s);
      s = fmaf(w3[ci * 4 + kb], b2f(pb[e]), s);
    }
  }
  out[(size_t)n * 4096 + ot] = s;
}

// ======================= VQ =======================
__global__ void ee_kernel(const float* __restrict__ emb, float* __restrict__ ee) {
  int c = blockIdx.x * 256 + threadIdx.x;
  if (c >= 512) return;
  float s = 0.0f;
  #pragma unroll
  for (int d = 0; d < 64; ++d) { float v = emb[c * 64 + d]; s = fmaf(v, v, s); }
  ee[c] = s;
}

__global__ __launch_bounds__(128)
void vq_argmin(const ushort* __restrict__ zt, const float* __restrict__ emb,
               const float* __restrict__ ee, int* __restrict__ idx,
               int* __restrict__ hist, float* __restrict__ loss_accum) {
  __shared__ float es[128 * 64];
  __shared__ float ees[128];
  __shared__ int lhist[512];
  __shared__ float lsum[2];
  const int tid = threadIdx.x;
  const int r = blockIdx.x * 128 + tid;
  float z[64];
  float zz = 0.0f;
  const uint4* zr = reinterpret_cast<const uint4*>(zt + (size_t)r * 64);
  #pragma unroll
  for (int i = 0; i < 8; ++i) {
    uint4 v = zr[i];
    const ushort* pv = reinterpret_cast<const ushort*>(&v);
    #pragma unroll
    for (int e = 0; e < 8; ++e) {
      float f = b2f(pv[e]);
      z[i * 8 + e] = f;
      zz = fmaf(f, f, zz);
    }
  }
  for (int l = tid; l < 512; l += 128) lhist[l] = 0;
  float best = 3.4e38f;
  int bi = 0;
  for (int c0 = 0; c0 < 512; c0 += 128) {
    __syncthreads();
    for (int l = tid; l < 128 * 64; l += 128) es[l] = emb[(size_t)c0 * 64 + l];
    if (tid < 128) ees[tid] = ee[c0 + tid];
    __syncthreads();
    for (int cc = 0; cc < 128; ++cc) {
      const float4* e4 = reinterpret_cast<const float4*>(es + cc * 64);
      float dot = 0.0f;
      #pragma unroll
      for (int i = 0; i < 16; ++i) {
        float4 e = e4[i];
        dot += z[4 * i] * e.x + z[4 * i + 1] * e.y + z[4 * i + 2] * e.z + z[4 * i + 3] * e.w;
      }
      float d = ees[cc] - 2.0f * dot;
      if (d < best) { best = d; bi = c0 + cc; }
    }
  }
  idx[r] = bi;
  atomicAdd(&lhist[bi], 1);
  float v = zz + best;
  for (int off = 32; off > 0; off >>= 1) v += __shfl_down(v, off);
  if ((tid & 63) == 0) lsum[tid >> 6] = v;
  __syncthreads();
  if (tid == 0) atomicAdd(loss_accum, lsum[0] + lsum[1]);
  for (int l = tid; l < 512; l += 128)
    if (lhist[l]) atomicAdd(&hist[l], lhist[l]);
}

__global__ __launch_bounds__(256)
void gather_q(const int* __restrict__ idx, const float* __restrict__ emb,
              ushort* __restrict__ q) {
  // q (B,256,64) bf16
  int o = blockIdx.x * 256 + threadIdx.x;
  int d = o & 63;
  int t = (o >> 6) & 255;
  int n = o >> 14;
  int id = idx[(n << 8) + t];
  q[o] = f2b(emb[id * 64 + d]);
}

__global__ __launch_bounds__(512)
void finalize(const int* __restrict__ hist, const float* __restrict__ loss_accum,
              float* __restrict__ out) {
  __shared__ float red[8];
  int tid = threadIdx.x;
  float avg = (float)hist[tid] * (1.0f / 65536.0f);
  float v = avg * logf(avg + 1e-10f);
  for (int off = 32; off > 0; off >>= 1) v += __shfl_down(v, off);
  if ((tid & 63) == 0) red[tid >> 6] = v;
  __syncthreads();
  if (tid == 0) {
    float s = 0.0f;
    for (int i = 0; i < 8; ++i) s += red[i];
    out[1048577] = expf(-s);
    out[0] = 1.25f * loss_accum[0] * (1.0f / (65536.0f * 64.0f));
  }
}

// ======================= launcher =======================
extern "C" void kernel_launch(void* const* d_in, const int* in_sizes, int n_in,
                              void* d_out, int out_size, void* d_ws, size_t ws_size,
                              hipStream_t stream) {
  (void)in_sizes; (void)n_in; (void)out_size; (void)ws_size;
  const float* x    = (const float*)d_in[0];
  const float* c1w  = (const float*)d_in[1];
  const float* c1b  = (const float*)d_in[2];
  const float* c2w  = (const float*)d_in[3];
  const float* c2b  = (const float*)d_in[4];
  const float* c3w  = (const float*)d_in[5];
  const float* c3b  = (const float*)d_in[6];
  const float* c4w  = (const float*)d_in[7];
  const float* c4b  = (const float*)d_in[8];
  const float* cfw  = (const float*)d_in[9];
  const float* cfb  = (const float*)d_in[10];
  const float* erw1 = (const float*)d_in[11];
  const float* erw2 = (const float*)d_in[12];
  const float* pqw  = (const float*)d_in[13];
  const float* pqb  = (const float*)d_in[14];
  const float* emb  = (const float*)d_in[15];
  const float* diw  = (const float*)d_in[16];
  const float* dib  = (const float*)d_in[17];
  const float* drw1 = (const float*)d_in[18];
  const float* drw2 = (const float*)d_in[19];
  const float* t0w  = (const float*)d_in[20];
  const float* t0b  = (const float*)d_in[21];
  const float* t1w  = (const float*)d_in[22];
  const float* t1b  = (const float*)d_in[23];
  const float* t2w  = (const float*)d_in[24];
  const float* t2b  = (const float*)d_in[25];
  const float* t3w  = (const float*)d_in[26];
  const float* t3b  = (const float*)d_in[27];

  char* wsb = (char*)d_ws;
  ushort* R0 = (ushort*)wsb;                           // 67,108,864 B: e1 ; later ct1-out
  ushort* R1 = (ushort*)(wsb + 67108864);              // 67,108,864 B: e2 ; later ct2-out
  ushort* R2 = (ushort*)(wsb + 134217728);             // 33,554,432 B: e3 ; later ct0-out
  // carved inside R0 (e1 dead after enc2; region reused by ct1 only after these die):
  ushort* R3 = (ushort*)(wsb + 0);                     // 16.7MB: e4 / dec ping
  ushort* R4 = (ushort*)(wsb + 16777216);              // 16.7MB: cf / dec pong
  ushort* R5 = (ushort*)(wsb + 33554432);              // 4.2MB: res hidden (B,256,32)
  ushort* R6 = (ushort*)(wsb + 37748736);              // 8.4MB: zt (BT,64)
  ushort* R7 = (ushort*)(wsb + 46137344);              // 8.4MB: qb (B,256,64)
  // weights (bf16) region:
  ushort* WPu = (ushort*)(wsb + 167772160);
  ushort* wb_e2 = WPu + 0;        // 32768
  ushort* wb_e3 = WPu + 32768;    // 65536
  ushort* wb_e4 = WPu + 98304;    // 65536
  ushort* wb_cf = WPu + 163840;   // 49152
  ushort* wb_r1a = WPu + 212992;  // 12288
  ushort* wb_r1b = WPu + 225280;  // 12288
  ushort* wb_r2a = WPu + 237568;  // 4096
  ushort* wb_r2b = WPu + 241664;  // 4096
  ushort* wb_pq = WPu + 245760;   // 8192
  ushort* wb_di = WPu + 253952;   // 24576
  ushort* wb_d1a = WPu + 278528;  // 12288
  ushort* wb_d1b = WPu + 290816;  // 12288
  ushort* wb_d2a = WPu + 303104;  // 4096
  ushort* wb_d2b = WPu + 307200;  // 4096
  ushort* wb_t0 = WPu + 311296;   // 65536
  ushort* wb_t1 = WPu + 376832;   // 65536
  ushort* wb_t2 = WPu + 442368;   // 32768  (end 475136)
  char* fp = wsb + 167772160 + 950272;
  float* eeb   = (float*)fp;                  // 512 f32
  int*   idxb  = (int*)(fp + 2048);           // 65536 int
  int*   histb = (int*)(fp + 2048 + 262144);  // 512 int
  float* lossb = (float*)(fp + 2048 + 262144 + 2048);
  float* outp  = (float*)d_out;

  hipMemsetAsync(histb, 0, 512 * sizeof(int), stream);
  hipMemsetAsync(lossb, 0, sizeof(float), stream);

  // ---- weight prep (single kernel) ----
  PrepArgs pa{};
  int nw = 0, total = 0;
  auto addw = [&](const float* src, ushort* dst, int CO, int CI, int K,
                  int sco, int sci, int sk) {
    pa.tot[nw] = K * CO * CI; pa.src[nw] = src; pa.dst[nw] = dst;
    pa.ci[nw] = CI; pa.co[nw] = CO; pa.sco[nw] = sco; pa.sci[nw] = sci; pa.sk[nw] = sk;
    total += pa.tot[nw]; ++nw;
  };
  // forward convs: w (CO,CI,K): sco=CI*K, sci=K, sk=1
  addw(c2w, wb_e2, 128, 64, 4, 256, 4, 1);
  addw(c3w, wb_e3, 128, 128, 4, 512, 4, 1);
  addw(c4w, wb_e4, 128, 128, 4, 512, 4, 1);
  addw(cfw, wb_cf, 128, 128, 3, 384, 3, 1);
  addw(erw1, wb_r1a, 32, 128, 3, 384, 3, 1);
  addw(erw1 + 12288, wb_r1b, 32, 128, 3, 384, 3, 1);
  addw(erw2, wb_r2a, 128, 32, 1, 32, 1, 1);
  addw(erw2 + 4096, wb_r2b, 128, 32, 1, 32, 1, 1);
  addw(pqw, wb_pq, 64, 128, 1, 128, 1, 1);
  addw(diw, wb_di, 128, 64, 3, 192, 3, 1);
  addw(drw1, wb_d1a, 32, 128, 3, 384, 3, 1);
  addw(drw1 + 12288, wb_d1b, 32, 128, 3, 384, 3, 1);
  addw(drw2, wb_d2a, 128, 32, 1, 32, 1, 1);
  addw(drw2 + 4096, wb_d2b, 128, 32, 1, 32, 1, 1);
  // transposed convs: w (CI,CO,4): sci=CO*4, sco=4, sk=1
  addw(t0w, wb_t0, 128, 128, 4, 4, 512, 1);
  addw(t1w, wb_t1, 128, 128, 4, 4, 512, 1);
  addw(t2w, wb_t2, 64, 128, 4, 4, 256, 1);
  pa.nw = nw;
  prep_all<<<(total + 255) / 256, 256, 0, stream>>>(pa, total);
  ee_kernel<<<2, 256, 0, stream>>>(emb, eeb);

  // ---- encoder ----
  enc1_bf<<<2048, 256, 0, stream>>>(x, c1w, c1b, R0);                                   // e1 (B,2048,64)
  conv_mfma<64, 128, 4, 2, true><<<4096, 256, 0, stream>>>(R0, wb_e2, c2b, nullptr, R1, 2048, 0, 1);
  conv_mfma<128, 128, 4, 2, true><<<2048, 256, 0, stream>>>(R1, wb_e3, c3b, nullptr, R2, 1024, 0, 1);
  conv_mfma<128, 128, 4, 2, true><<<1024, 256, 0, stream>>>(R2, wb_e4, c4b, nullptr, R3, 512, 0, 1);
  conv_mfma<128, 128, 3, 1, true><<<1024, 256, 0, stream>>>(R3, wb_cf, cfb, nullptr, R4, 256, 0, 0);
  // encoder residual stack
  conv_mfma<128, 32, 3, 1, true><<<1024, 256, 0, stream>>>(R4, wb_r1a, nullptr, nullptr, R5, 256, 1, 0);
  conv_mfma<32, 128, 1, 1, false><<<1024, 256, 0, stream>>>(R5, wb_r2a, nullptr, R4, R3, 256, 1, 0);
  conv_mfma<128, 32, 3, 1, true><<<1024, 256, 0, stream>>>(R3, wb_r1b, nullptr, nullptr, R5, 256, 1, 0);
  conv_mfma<32, 128, 1, 1, false><<<1024, 256, 0, stream>>>(R5, wb_r2b, nullptr, R3, R4, 256, 1, 0);
  // pre-VQ 1x1 (+ final res relu via in_relu) -> zt (BT,64)
  conv_mfma<128, 64, 1, 1, false><<<1024, 256, 0, stream>>>(R4, wb_pq, pqb, nullptr, R6, 256, 1, 0);
  // ---- VQ ----
  vq_argmin<<<512, 128, 0, stream>>>(R6, emb, eeb, idxb, histb, lossb);
  gather_q<<<16384, 256, 0, stream>>>(idxb, emb, R7);
  finalize<<<1, 512, 0, stream>>>(histb, lossb, outp);
  // ---- decoder ----
  conv_mfma<64, 128, 3, 1, false><<<1024, 256, 0, stream>>>(R7, wb_di, dib, nullptr, R3, 256, 0, 0);
  conv_mfma<128, 32, 3, 1, true><<<1024, 256, 0, stream>>>(R3, wb_d1a, nullptr, nullptr, R5, 256, 1, 0);
  conv_mfma<32, 128, 1, 1, false><<<1024, 256, 0, stream>>>(R5, wb_d2a, nullptr, R3, R4, 256, 1, 0);
  conv_mfma<128, 32, 3, 1, true><<<1024, 256, 0, stream>>>(R4, wb_d1b, nullptr, nullptr, R5, 256, 1, 0);
  conv_mfma<32, 128, 1, 1, false><<<1024, 256, 0, stream>>>(R5, wb_d2b, nullptr, R4, R3, 256, 1, 0);
  convt_mfma<128><<<1024, 256, 0, stream>>>(R3, wb_t0, t0b, R2, 256, 1, 1);
  convt_mfma<128><<<2048, 256, 0, stream>>>(R2, wb_t1, t1b, R0, 512, 0, 1);
  convt_mfma<64><<<4096, 256, 0, stream>>>(R0, wb_t2, t2b, R1, 1024, 0, 1);
  ct3_bf<<<4096, 256, 0, stream>>>(R1, t3w, t3b, outp + 1);
}

// Round 4
// 520.442 us; speedup vs baseline: 5.7642x; 1.2161x over previous
//
#include <hip/hip_runtime.h>

#define DEVI __device__ __forceinline__

typedef __bf16 bf16x8 __attribute__((ext_vector_type(8)));
typedef float f32x4 __attribute__((ext_vector_type(4)));

DEVI ushort f2b(float f) {            // f32 -> bf16 RNE
  uint b = __float_as_uint(f);
  uint r = (b + 0x7FFFu + ((b >> 16) & 1u)) >> 16;
  return (ushort)r;
}
DEVI float b2f(ushort u) { return __uint_as_float(((uint)u) << 16); }

// ======================= weight prep: all convs -> bf16 Wb[tap][co][ci] =======================
struct PrepArgs {
  int nw;
  int tot[20];
  const float* src[20];
  ushort* dst[20];
  int ci[20], co[20], sco[20], sci[20], sk[20];
};

__global__ __launch_bounds__(256)
void prep_all(PrepArgs a, int total) {
  int i = blockIdx.x * 256 + threadIdx.x;
  if (i >= total) return;
  int w = 0;
  while (i >= a.tot[w]) { i -= a.tot[w]; ++w; }
  const int li = i;
  const int CI = a.ci[w];
  int ciX = i % CI;
  int rest = i / CI;
  int coX = rest % a.co[w];
  int k = rest / a.co[w];
  a.dst[w][li] = f2b(a.src[w][coX * a.sco[w] + ciX * a.sci[w] + k * a.sk[w]]);
}

// ======================= enc1 scalar: x(f32,B,1,4096) -> (B,2048,64) bf16, relu ================
__global__ __launch_bounds__(256)
void enc1_bf(const float* __restrict__ x, const float* __restrict__ w1,
             const float* __restrict__ b1, ushort* __restrict__ out) {
  int i = blockIdx.x * 256 + threadIdx.x;    // (n,t): 256*2048
  int t = i & 2047, n = i >> 11;
  const float* xb = x + ((size_t)n << 12);
  int p = 2 * t - 1;
  float x0 = xb[(p + 4096) & 4095];
  float x1 = xb[(p + 4097) & 4095];
  float x2 = xb[(p + 4098) & 4095];
  float x3 = xb[(p + 4099) & 4095];
  uint ow[32];
  #pragma unroll
  for (int c2 = 0; c2 < 32; ++c2) {
    float4 wa = *reinterpret_cast<const float4*>(w1 + 8 * c2);
    float4 wb = *reinterpret_cast<const float4*>(w1 + 8 * c2 + 4);
    float s0 = fmaf(wa.x, x0, fmaf(wa.y, x1, fmaf(wa.z, x2, fmaf(wa.w, x3, b1[2 * c2]))));
    float s1 = fmaf(wb.x, x0, fmaf(wb.y, x1, fmaf(wb.z, x2, fmaf(wb.w, x3, b1[2 * c2 + 1]))));
    ow[c2] = (uint)f2b(fmaxf(s0, 0.0f)) | ((uint)f2b(fmaxf(s1, 0.0f)) << 16);
  }
  uint4* op = reinterpret_cast<uint4*>(out + ((size_t)i << 6));
  #pragma unroll
  for (int q = 0; q < 8; ++q)
    op[q] = uint4{ow[4 * q], ow[4 * q + 1], ow[4 * q + 2], ow[4 * q + 3]};
}

// ======================= MFMA forward conv =======================
// in (B,Tin,CI) bf16 -> out (B,Tout,CO) bf16.  Wb layout: [tap][co][ci] bf16.
// A = X (M=t, K=ci), B = W (K=ci, N=co). 16x16x32 bf16 MFMA.
template<int CI, int CO, int K, int S, bool CIRC>
__global__ __launch_bounds__(256)
void conv_mfma(const ushort* __restrict__ in, const ushort* __restrict__ wb,
               const float* __restrict__ bias, const ushort* __restrict__ resid,
               ushort* __restrict__ out, int Tin, int in_relu, int out_relu) {
  constexpr int PAD = (K > 1) ? 1 : 0;
  constexpr int NT = 4;                       // 4 t-tiles = 64 outputs / block
  constexpr int TT = NT * 16;
  constexpr int SPAN = S * (TT - 1) + K;
  constexpr int CIG = CI / 8;                 // 16B granules per row
  constexpr int COT = CO / 16;
  constexpr int WCOT = (COT + 3) / 4;         // co-tiles per wave: 128->2, 64->1, 32->1
  constexpr int WAVES_CO = COT / WCOT;        // 4,4,2
  constexpr int WAVES_T = 4 / WAVES_CO;       // 1,1,2
  constexpr int WTT = NT / WAVES_T;           // 4,4,2
  static_assert(CI % 32 == 0, "");

  __shared__ __align__(16) ushort xs[SPAN * CI];

  const int Tout = Tin / S;
  const int tilesPerB = Tout / TT;
  const int n = blockIdx.x / tilesPerB;
  const int t0 = (blockIdx.x % tilesPerB) * TT;
  const int tid = threadIdx.x;
  const int wid = tid >> 6, lane = tid & 63;
  const int l15 = lane & 15, l4 = lane >> 4;

  // ---- stage X tile: rows t_in0..t_in0+SPAN-1 into [t][ci] with granule swizzle ----
  const int t_in0 = S * t0 - PAD;
  const ushort* inb = in + (size_t)n * Tin * CI;
  for (int i = tid; i < SPAN * CIG; i += 256) {
    int t = i / CIG, g = i - (i / CIG) * CIG;
    int tg = t_in0 + t;
    uint4 v;
    if (CIRC) {
      tg = (tg < 0) ? tg + Tin : (tg >= Tin ? tg - Tin : tg);
      v = *reinterpret_cast<const uint4*>(inb + (size_t)tg * CI + g * 8);
    } else {
      if ((unsigned)tg < (unsigned)Tin)
        v = *reinterpret_cast<const uint4*>(inb + (size_t)tg * CI + g * 8);
      else
        v = uint4{0, 0, 0, 0};
    }
    if (in_relu) {
      ushort* pv = reinterpret_cast<ushort*>(&v);
      #pragma unroll
      for (int e = 0; e < 8; ++e) pv[e] = (pv[e] & 0x8000) ? 0 : pv[e];
    }
    *reinterpret_cast<uint4*>(&xs[t * CI + ((g ^ (t & (CIG - 1))) * 8)]) = v;
  }
  __syncthreads();

  const int wco = wid % WAVES_CO;
  const int wt = wid / WAVES_CO;
  const int co_base = wco * WCOT * 16;
  const int t_base = wt * WTT * 16;

  f32x4 acc[WTT][WCOT] = {};

  for (int cc = 0; cc < CI / 32; ++cc) {
    #pragma unroll
    for (int k = 0; k < K; ++k) {
      bf16x8 bfr[WCOT];
      #pragma unroll
      for (int c = 0; c < WCOT; ++c) {
        const ushort* wp = wb + (size_t)((k * CO + co_base + c * 16 + l15)) * CI + cc * 32 + l4 * 8;
        bfr[c] = __builtin_bit_cast(bf16x8, *reinterpret_cast<const uint4*>(wp));
      }
      #pragma unroll
      for (int tt2 = 0; tt2 < WTT; ++tt2) {
        int trow = S * (t_base + tt2 * 16 + l15) + k;
        int g = cc * 4 + l4;
        bf16x8 afr = __builtin_bit_cast(bf16x8, *reinterpret_cast<const uint4*>(
            &xs[trow * CI + ((g ^ (trow & (CIG - 1))) * 8)]));
        #pragma unroll
        for (int c = 0; c < WCOT; ++c)
          acc[tt2][c] = __builtin_amdgcn_mfma_f32_16x16x32_bf16(afr, bfr[c], acc[tt2][c], 0, 0, 0);
      }
    }
  }

  float bv[WCOT];
  #pragma unroll
  for (int c = 0; c < WCOT; ++c)
    bv[c] = bias ? bias[co_base + c * 16 + l15] : 0.0f;
  ushort* outb = out + (size_t)n * Tout * CO;
  const ushort* resb = resid ? resid + (size_t)n * Tout * CO : nullptr;
  #pragma unroll
  for (int tt2 = 0; tt2 < WTT; ++tt2)
    #pragma unroll
    for (int c = 0; c < WCOT; ++c)
      #pragma unroll
      for (int r = 0; r < 4; ++r) {
        int t = t0 + t_base + tt2 * 16 + 4 * l4 + r;
        int co = co_base + c * 16 + l15;
        float v = acc[tt2][c][r] + bv[c];
        if (resb) v += b2f(resb[(size_t)t * CO + co]);
        if (out_relu) v = fmaxf(v, 0.0f);
        outb[(size_t)t * CO + co] = f2b(v);
      }
}

// ======================= MFMA transposed conv k=4 s=2 p=1 (CI=128) =======================
// even ot=2t': taps w[k=1]@t', w[k=3]@t'-1 ; odd ot=2t'+1: w[k=0]@t'+1, w[k=2]@t'
template<int CO>
__global__ __launch_bounds__(256)
void convt_mfma(const ushort* __restrict__ in, const ushort* __restrict__ wb,
                const float* __restrict__ bias, ushort* __restrict__ out,
                int Tin, int in_relu, int out_relu) {
  constexpr int CI = 128, CIG = 16;
  constexpr int NT = 4, TT = 64;              // 64 t' -> 128 outputs / block
  constexpr int SPAN = TT + 2;
  constexpr int COT = CO / 16;
  constexpr int WCOT = (COT + 3) / 4;         // 128->2, 64->1
  constexpr int WAVES_CO = COT / WCOT;        // 4
  constexpr int WTT = NT;                     // 4 (WAVES_T = 1)

  __shared__ __align__(16) ushort xs[SPAN * CI];

  const int Tout = 2 * Tin;
  const int tilesPerB = Tin / TT;
  const int n = blockIdx.x / tilesPerB;
  const int tp0 = (blockIdx.x % tilesPerB) * TT;
  const int tid = threadIdx.x;
  const int wid = tid >> 6, lane = tid & 63;
  const int l15 = lane & 15, l4 = lane >> 4;

  const int t_in0 = tp0 - 1;
  const ushort* inb = in + (size_t)n * Tin * CI;
  for (int i = tid; i < SPAN * CIG; i += 256) {
    int t = i >> 4, g = i & 15;
    int tg = t_in0 + t;
    uint4 v;
    if ((unsigned)tg < (unsigned)Tin)
      v = *reinterpret_cast<const uint4*>(inb + (size_t)tg * CI + g * 8);
    else
      v = uint4{0, 0, 0, 0};
    if (in_relu) {
      ushort* pv = reinterpret_cast<ushort*>(&v);
      #pragma unroll
      for (int e = 0; e < 8; ++e) pv[e] = (pv[e] & 0x8000) ? 0 : pv[e];
    }
    *reinterpret_cast<uint4*>(&xs[t * CI + ((g ^ (t & 15)) * 8)]) = v;
  }
  __syncthreads();

  const int wco = wid % WAVES_CO;
  const int co_base = wco * WCOT * 16;

  f32x4 accE[WTT][WCOT] = {};
  f32x4 accO[WTT][WCOT] = {};

  for (int cc = 0; cc < 4; ++cc) {
    bf16x8 bk[4][WCOT];
    #pragma unroll
    for (int k = 0; k < 4; ++k)
      #pragma unroll
      for (int c = 0; c < WCOT; ++c) {
        const ushort* wp = wb + (size_t)((k * CO + co_base + c * 16 + l15)) * CI + cc * 32 + l4 * 8;
        bk[k][c] = __builtin_bit_cast(bf16x8, *reinterpret_cast<const uint4*>(wp));
      }
    #pragma unroll
    for (int tt2 = 0; tt2 < WTT; ++tt2) {
      int lt = tt2 * 16 + l15 + 1;            // local row of t' in xs
      int g = cc * 4 + l4;
      bf16x8 a0 = __builtin_bit_cast(bf16x8, *reinterpret_cast<const uint4*>(
          &xs[lt * CI + ((g ^ (lt & 15)) * 8)]));
      bf16x8 am = __builtin_bit_cast(bf16x8, *reinterpret_cast<const uint4*>(
          &xs[(lt - 1) * CI + ((g ^ ((lt - 1) & 15)) * 8)]));
      bf16x8 ap = __builtin_bit_cast(bf16x8, *reinterpret_cast<const uint4*>(
          &xs[(lt + 1) * CI + ((g ^ ((lt + 1) & 15)) * 8)]));
      #pragma unroll
      for (int c = 0; c < WCOT; ++c) {
        accE[tt2][c] = __builtin_amdgcn_mfma_f32_16x16x32_bf16(a0, bk[1][c], accE[tt2][c], 0, 0, 0);
        accE[tt2][c] = __builtin_amdgcn_mfma_f32_16x16x32_bf16(am, bk[3][c], accE[tt2][c], 0, 0, 0);
        accO[tt2][c] = __builtin_amdgcn_mfma_f32_16x16x32_bf16(ap, bk[0][c], accO[tt2][c], 0, 0, 0);
        accO[tt2][c] = __builtin_amdgcn_mfma_f32_16x16x32_bf16(a0, bk[2][c], accO[tt2][c], 0, 0, 0);
      }
    }
  }

  float bv[WCOT];
  #pragma unroll
  for (int c = 0; c < WCOT; ++c) bv[c] = bias[co_base + c * 16 + l15];
  ushort* outb = out + (size_t)n * Tout * CO;
  #pragma unroll
  for (int tt2 = 0; tt2 < WTT; ++tt2)
    #pragma unroll
    for (int c = 0; c < WCOT; ++c)
      #pragma unroll
      for (int r = 0; r < 4; ++r) {
        int tp = tp0 + tt2 * 16 + 4 * l4 + r;
        int co = co_base + c * 16 + l15;
        float vE = accE[tt2][c][r] + bv[c];
        float vO = accO[tt2][c][r] + bv[c];
        if (out_relu) { vE = fmaxf(vE, 0.0f); vO = fmaxf(vO, 0.0f); }
        outb[(size_t)(2 * tp) * CO + co] = f2b(vE);
        outb[(size_t)(2 * tp + 1) * CO + co] = f2b(vO);
      }
}

// ======================= ct3 scalar: (B,2048,64) bf16 -> (B,4096) f32 =======================
__global__ __launch_bounds__(256)
void ct3_bf(const ushort* __restrict__ in, const float* __restrict__ w3,
            const float* __restrict__ b3, float* __restrict__ out) {
  constexpr int SPAN = 130;
  __shared__ __align__(16) ushort ys[SPAN * 64];
  const int n = blockIdx.x >> 4;
  const int ot0 = (blockIdx.x & 15) << 8;   // 256 outputs / block
  const int tid = threadIdx.x;
  const int t_in0 = (ot0 >> 1) - 1;
  const ushort* inb = in + (size_t)n * 2048 * 64;
  for (int i = tid; i < SPAN * 8; i += 256) {
    int t = i >> 3, g = i & 7;
    int tg = t_in0 + t;
    uint4 v;
    if ((unsigned)tg < 2048u)
      v = *reinterpret_cast<const uint4*>(inb + (size_t)tg * 64 + g * 8);
    else
      v = uint4{0, 0, 0, 0};
    *reinterpret_cast<uint4*>(&ys[t * 64 + ((g ^ (t & 7)) * 8)]) = v;
  }
  __syncthreads();
  const int ot = ot0 + tid;
  const int odd = ot & 1;
  const int it_a = odd ? ((ot + 1) >> 1) : (ot >> 1);
  const int it_b = odd ? ((ot - 1) >> 1) : (ot / 2 - 1);
  const int ka = odd ? 0 : 1;
  const int kb = odd ? 2 : 3;
  const int lt_a = it_a - t_in0, lt_b = it_b - t_in0;
  float s = b3[0];
  #pragma unroll
  for (int g = 0; g < 8; ++g) {
    uint4 va = *reinterpret_cast<const uint4*>(&ys[lt_a * 64 + ((g ^ (lt_a & 7)) * 8)]);
    uint4 vb = *reinterpret_cast<const uint4*>(&ys[lt_b * 64 + ((g ^ (lt_b & 7)) * 8)]);
    const ushort* pa = reinterpret_cast<const ushort*>(&va);
    const ushort* pb = reinterpret_cast<const ushort*>(&vb);
    #pragma unroll
    for (int e = 0; e < 8; ++e) {
      int ci = g * 8 + e;
      s = fmaf(w3[ci * 4 + ka], b2f(pa[e]), s);
      s = fmaf(w3[ci * 4 + kb], b2f(pb[e]), s);
    }
  }
  out[(size_t)n * 4096 + ot] = s;
}

// ======================= VQ =======================
__global__ void ee_kernel(const float* __restrict__ emb, float* __restrict__ ee) {
  int c = blockIdx.x * 256 + threadIdx.x;
  if (c >= 512) return;
  float s = 0.0f;
  #pragma unroll
  for (int d = 0; d < 64; ++d) { float v = emb[c * 64 + d]; s = fmaf(v, v, s); }
  ee[c] = s;
}

// MFMA VQ: S = emb @ z^T via 16x16x32. A=emb (M=code), B=z (N=row).
// C layout: col=l15 -> z-row, row=l4*4+r -> code. Argmin over codes is
// per-lane (register) + shfl_xor(16,32) merge. 4 waves x 16 rows = 64 rows/block.
__global__ __launch_bounds__(256)
void vq_mfma(const ushort* __restrict__ zt, const ushort* __restrict__ embb,
             const float* __restrict__ ee, int* __restrict__ idx,
             int* __restrict__ hist, float* __restrict__ loss_accum) {
  __shared__ __align__(16) ushort es[512 * 64];   // 64 KB, granule-swizzled
  __shared__ float eel[512];
  __shared__ int lhist[512];
  const int tid = threadIdx.x;
  const int wid = tid >> 6, lane = tid & 63;
  const int l15 = lane & 15, l4 = lane >> 4;

  for (int i = tid; i < 512 * 8; i += 256) {      // 4096 uint4 granules
    int c = i >> 3, g = i & 7;
    reinterpret_cast<uint4*>(es)[c * 8 + (g ^ (c & 7))] =
        reinterpret_cast<const uint4*>(embb)[i];
  }
  for (int i = tid; i < 512; i += 256) { eel[i] = ee[i]; lhist[i] = 0; }
  __syncthreads();

  const int r = blockIdx.x * 64 + wid * 16 + l15;
  // B fragments (z row r), k = kk*32 + l4*8; plus zz = ||z_r||^2
  bf16x8 bz[2];
  float zz;
  {
    uint4 v0 = *reinterpret_cast<const uint4*>(zt + (size_t)r * 64 + l4 * 8);
    uint4 v1 = *reinterpret_cast<const uint4*>(zt + (size_t)r * 64 + 32 + l4 * 8);
    bz[0] = __builtin_bit_cast(bf16x8, v0);
    bz[1] = __builtin_bit_cast(bf16x8, v1);
    float s = 0.0f;
    const ushort* p0 = reinterpret_cast<const ushort*>(&v0);
    const ushort* p1 = reinterpret_cast<const ushort*>(&v1);
    #pragma unroll
    for (int e = 0; e < 8; ++e) {
      float f0 = b2f(p0[e]), f1 = b2f(p1[e]);
      s = fmaf(f0, f0, fmaf(f1, f1, s));
    }
    s += __shfl_xor(s, 16);
    s += __shfl_xor(s, 32);
    zz = s;
  }

  float best = 3.4e38f;
  int bi = 0;
  for (int ct = 0; ct < 32; ++ct) {
    const int c = ct * 16 + l15;
    bf16x8 a0 = __builtin_bit_cast(bf16x8, reinterpret_cast<const uint4*>(es)[
        c * 8 + (l4 ^ (c & 7))]);
    bf16x8 a1 = __builtin_bit_cast(bf16x8, reinterpret_cast<const uint4*>(es)[
        c * 8 + ((4 | l4) ^ (c & 7))]);
    f32x4 acc = {};
    acc = __builtin_amdgcn_mfma_f32_16x16x32_bf16(a0, bz[0], acc, 0, 0, 0);
    acc = __builtin_amdgcn_mfma_f32_16x16x32_bf16(a1, bz[1], acc, 0, 0, 0);
    #pragma unroll
    for (int rr = 0; rr < 4; ++rr) {
      int code = ct * 16 + l4 * 4 + rr;
      float d = eel[code] - 2.0f * acc[rr];
      if (d < best || (d == best && code < bi)) { best = d; bi = code; }
    }
  }
  #pragma unroll
  for (int m = 16; m <= 32; m <<= 1) {
    float ob = __shfl_xor(best, m);
    int oi = __shfl_xor(bi, m);
    if (ob < best || (ob == best && oi < bi)) { best = ob; bi = oi; }
  }
  if (l4 == 0) {
    idx[r] = bi;
    atomicAdd(&lhist[bi], 1);
  }
  float v = (l4 == 0) ? (zz + best) : 0.0f;
  #pragma unroll
  for (int m = 1; m < 64; m <<= 1) v += __shfl_xor(v, m);
  if (lane == 0) atomicAdd(loss_accum, v);
  __syncthreads();
  for (int i = tid; i < 512; i += 256)
    if (lhist[i]) atomicAdd(&hist[i], lhist[i]);
}

__global__ __launch_bounds__(256)
void gather_q(const int* __restrict__ idx, const float* __restrict__ emb,
              ushort* __restrict__ q) {
  // q (B,256,64) bf16
  int o = blockIdx.x * 256 + threadIdx.x;
  int d = o & 63;
  int t = (o >> 6) & 255;
  int n = o >> 14;
  int id = idx[(n << 8) + t];
  q[o] = f2b(emb[id * 64 + d]);
}

__global__ __launch_bounds__(512)
void finalize(const int* __restrict__ hist, const float* __restrict__ loss_accum,
              float* __restrict__ out) {
  __shared__ float red[8];
  int tid = threadIdx.x;
  float avg = (float)hist[tid] * (1.0f / 65536.0f);
  float v = avg * logf(avg + 1e-10f);
  for (int off = 32; off > 0; off >>= 1) v += __shfl_down(v, off);
  if ((tid & 63) == 0) red[tid >> 6] = v;
  __syncthreads();
  if (tid == 0) {
    float s = 0.0f;
    for (int i = 0; i < 8; ++i) s += red[i];
    out[1048577] = expf(-s);
    out[0] = 1.25f * loss_accum[0] * (1.0f / (65536.0f * 64.0f));
  }
}

// ======================= launcher =======================
extern "C" void kernel_launch(void* const* d_in, const int* in_sizes, int n_in,
                              void* d_out, int out_size, void* d_ws, size_t ws_size,
                              hipStream_t stream) {
  (void)in_sizes; (void)n_in; (void)out_size; (void)ws_size;
  const float* x    = (const float*)d_in[0];
  const float* c1w  = (const float*)d_in[1];
  const float* c1b  = (const float*)d_in[2];
  const float* c2w  = (const float*)d_in[3];
  const float* c2b  = (const float*)d_in[4];
  const float* c3w  = (const float*)d_in[5];
  const float* c3b  = (const float*)d_in[6];
  const float* c4w  = (const float*)d_in[7];
  const float* c4b  = (const float*)d_in[8];
  const float* cfw  = (const float*)d_in[9];
  const float* cfb  = (const float*)d_in[10];
  const float* erw1 = (const float*)d_in[11];
  const float* erw2 = (const float*)d_in[12];
  const float* pqw  = (const float*)d_in[13];
  const float* pqb  = (const float*)d_in[14];
  const float* emb  = (const float*)d_in[15];
  const float* diw  = (const float*)d_in[16];
  const float* dib  = (const float*)d_in[17];
  const float* drw1 = (const float*)d_in[18];
  const float* drw2 = (const float*)d_in[19];
  const float* t0w  = (const float*)d_in[20];
  const float* t0b  = (const float*)d_in[21];
  const float* t1w  = (const float*)d_in[22];
  const float* t1b  = (const float*)d_in[23];
  const float* t2w  = (const float*)d_in[24];
  const float* t2b  = (const float*)d_in[25];
  const float* t3w  = (const float*)d_in[26];
  const float* t3b  = (const float*)d_in[27];

  char* wsb = (char*)d_ws;
  ushort* R0 = (ushort*)wsb;                           // 67,108,864 B: e1 ; later ct1-out
  ushort* R1 = (ushort*)(wsb + 67108864);              // 67,108,864 B: e2 ; later ct2-out
  ushort* R2 = (ushort*)(wsb + 134217728);             // 33,554,432 B: e3 ; later ct0-out
  // carved inside R0 (e1 dead after enc2; region reused by ct1 only after these die):
  ushort* R3 = (ushort*)(wsb + 0);                     // 16.7MB: e4 / dec ping
  ushort* R4 = (ushort*)(wsb + 16777216);              // 16.7MB: cf / dec pong
  ushort* R5 = (ushort*)(wsb + 33554432);              // 4.2MB: res hidden (B,256,32)
  ushort* R6 = (ushort*)(wsb + 37748736);              // 8.4MB: zt (BT,64)
  ushort* R7 = (ushort*)(wsb + 46137344);              // 8.4MB: qb (B,256,64)
  // weights (bf16) region:
  ushort* WPu = (ushort*)(wsb + 167772160);
  ushort* wb_e2 = WPu + 0;        // 32768
  ushort* wb_e3 = WPu + 32768;    // 65536
  ushort* wb_e4 = WPu + 98304;    // 65536
  ushort* wb_cf = WPu + 163840;   // 49152
  ushort* wb_r1a = WPu + 212992;  // 12288
  ushort* wb_r1b = WPu + 225280;  // 12288
  ushort* wb_r2a = WPu + 237568;  // 4096
  ushort* wb_r2b = WPu + 241664;  // 4096
  ushort* wb_pq = WPu + 245760;   // 8192
  ushort* wb_di = WPu + 253952;   // 24576
  ushort* wb_d1a = WPu + 278528;  // 12288
  ushort* wb_d1b = WPu + 290816;  // 12288
  ushort* wb_d2a = WPu + 303104;  // 4096
  ushort* wb_d2b = WPu + 307200;  // 4096
  ushort* wb_t0 = WPu + 311296;   // 65536
  ushort* wb_t1 = WPu + 376832;   // 65536
  ushort* wb_t2 = WPu + 442368;   // 32768
  ushort* wb_emb = WPu + 475136;  // 32768 (end 507904)
  char* fp = wsb + 167772160 + 1048576;
  float* eeb   = (float*)fp;                  // 512 f32
  int*   idxb  = (int*)(fp + 2048);           // 65536 int
  int*   histb = (int*)(fp + 2048 + 262144);  // 512 int
  float* lossb = (float*)(fp + 2048 + 262144 + 2048);
  float* outp  = (float*)d_out;

  hipMemsetAsync(histb, 0, 512 * sizeof(int), stream);
  hipMemsetAsync(lossb, 0, sizeof(float), stream);

  // ---- weight prep (single kernel) ----
  PrepArgs pa{};
  int nw = 0, total = 0;
  auto addw = [&](const float* src, ushort* dst, int CO, int CI, int K,
                  int sco, int sci, int sk) {
    pa.tot[nw] = K * CO * CI; pa.src[nw] = src; pa.dst[nw] = dst;
    pa.ci[nw] = CI; pa.co[nw] = CO; pa.sco[nw] = sco; pa.sci[nw] = sci; pa.sk[nw] = sk;
    total += pa.tot[nw]; ++nw;
  };
  // forward convs: w (CO,CI,K): sco=CI*K, sci=K, sk=1
  addw(c2w, wb_e2, 128, 64, 4, 256, 4, 1);
  addw(c3w, wb_e3, 128, 128, 4, 512, 4, 1);
  addw(c4w, wb_e4, 128, 128, 4, 512, 4, 1);
  addw(cfw, wb_cf, 128, 128, 3, 384, 3, 1);
  addw(erw1, wb_r1a, 32, 128, 3, 384, 3, 1);
  addw(erw1 + 12288, wb_r1b, 32, 128, 3, 384, 3, 1);
  addw(erw2, wb_r2a, 128, 32, 1, 32, 1, 1);
  addw(erw2 + 4096, wb_r2b, 128, 32, 1, 32, 1, 1);
  addw(pqw, wb_pq, 64, 128, 1, 128, 1, 1);
  addw(diw, wb_di, 128, 64, 3, 192, 3, 1);
  addw(drw1, wb_d1a, 32, 128, 3, 384, 3, 1);
  addw(drw1 + 12288, wb_d1b, 32, 128, 3, 384, 3, 1);
  addw(drw2, wb_d2a, 128, 32, 1, 32, 1, 1);
  addw(drw2 + 4096, wb_d2b, 128, 32, 1, 32, 1, 1);
  // transposed convs: w (CI,CO,4): sci=CO*4, sco=4, sk=1
  addw(t0w, wb_t0, 128, 128, 4, 4, 512, 1);
  addw(t1w, wb_t1, 128, 128, 4, 4, 512, 1);
  addw(t2w, wb_t2, 64, 128, 4, 4, 256, 1);
  // codebook -> bf16 (identity layout)
  addw(emb, wb_emb, 512, 64, 1, 64, 1, 1);
  pa.nw = nw;
  prep_all<<<(total + 255) / 256, 256, 0, stream>>>(pa, total);
  ee_kernel<<<2, 256, 0, stream>>>(emb, eeb);

  // ---- encoder ----
  enc1_bf<<<2048, 256, 0, stream>>>(x, c1w, c1b, R0);                                   // e1 (B,2048,64)
  conv_mfma<64, 128, 4, 2, true><<<4096, 256, 0, stream>>>(R0, wb_e2, c2b, nullptr, R1, 2048, 0, 1);
  conv_mfma<128, 128, 4, 2, true><<<2048, 256, 0, stream>>>(R1, wb_e3, c3b, nullptr, R2, 1024, 0, 1);
  conv_mfma<128, 128, 4, 2, true><<<1024, 256, 0, stream>>>(R2, wb_e4, c4b, nullptr, R3, 512, 0, 1);
  conv_mfma<128, 128, 3, 1, true><<<1024, 256, 0, stream>>>(R3, wb_cf, cfb, nullptr, R4, 256, 0, 0);
  // encoder residual stack
  conv_mfma<128, 32, 3, 1, true><<<1024, 256, 0, stream>>>(R4, wb_r1a, nullptr, nullptr, R5, 256, 1, 0);
  conv_mfma<32, 128, 1, 1, false><<<1024, 256, 0, stream>>>(R5, wb_r2a, nullptr, R4, R3, 256, 1, 0);
  conv_mfma<128, 32, 3, 1, true><<<1024, 256, 0, stream>>>(R3, wb_r1b, nullptr, nullptr, R5, 256, 1, 0);
  conv_mfma<32, 128, 1, 1, false><<<1024, 256, 0, stream>>>(R5, wb_r2b, nullptr, R3, R4, 256, 1, 0);
  // pre-VQ 1x1 (+ final res relu via in_relu) -> zt (BT,64)
  conv_mfma<128, 64, 1, 1, false><<<1024, 256, 0, stream>>>(R4, wb_pq, pqb, nullptr, R6, 256, 1, 0);
  // ---- VQ ----
  vq_mfma<<<1024, 256, 0, stream>>>(R6, wb_emb, eeb, idxb, histb, lossb);
  gather_q<<<16384, 256, 0, stream>>>(idxb, emb, R7);
  finalize<<<1, 512, 0, stream>>>(histb, lossb, outp);
  // ---- decoder ----
  conv_mfma<64, 128, 3, 1, false><<<1024, 256, 0, stream>>>(R7, wb_di, dib, nullptr, R3, 256, 0, 0);
  conv_mfma<128, 32, 3, 1, true><<<1024, 256, 0, stream>>>(R3, wb_d1a, nullptr, nullptr, R5, 256, 1, 0);
  conv_mfma<32, 128, 1, 1, false><<<1024, 256, 0, stream>>>(R5, wb_d2a, nullptr, R3, R4, 256, 1, 0);
  conv_mfma<128, 32, 3, 1, true><<<1024, 256, 0, stream>>>(R4, wb_d1b, nullptr, nullptr, R5, 256, 1, 0);
  conv_mfma<32, 128, 1, 1, false><<<1024, 256, 0, stream>>>(R5, wb_d2b, nullptr, R4, R3, 256, 1, 0);
  convt_mfma<128><<<1024, 256, 0, stream>>>(R3, wb_t0, t0b, R2, 256, 1, 1);
  convt_mfma<128><<<2048, 256, 0, stream>>>(R2, wb_t1, t1b, R0, 512, 0, 1);
  convt_mfma<64><<<4096, 256, 0, stream>>>(R0, wb_t2, t2b, R1, 1024, 0, 1);
  ct3_bf<<<4096, 256, 0, stream>>>(R1, t3w, t3b, outp + 1);
}

// Round 5
// 463.555 us; speedup vs baseline: 6.4716x; 1.1227x over previous
//
#include <hip/hip_runtime.h>

#define DEVI __device__ __forceinline__

typedef __bf16 bf16x8 __attribute__((ext_vector_type(8)));
typedef float f32x4 __attribute__((ext_vector_type(4)));

DEVI ushort f2b(float f) {            // f32 -> bf16 RNE
  uint b = __float_as_uint(f);
  uint r = (b + 0x7FFFu + ((b >> 16) & 1u)) >> 16;
  return (ushort)r;
}
DEVI float b2f(ushort u) { return __uint_as_float(((uint)u) << 16); }

// ======================= weight prep: all convs -> bf16 Wb[tap][co][ci] =======================
struct PrepArgs {
  int nw;
  int tot[20];
  const float* src[20];
  ushort* dst[20];
  int ci[20], co[20], sco[20], sci[20], sk[20];
};

__global__ __launch_bounds__(256)
void prep_all(PrepArgs a, int total) {
  int i = blockIdx.x * 256 + threadIdx.x;
  if (i >= total) return;
  int w = 0;
  while (i >= a.tot[w]) { i -= a.tot[w]; ++w; }
  const int li = i;
  const int CI = a.ci[w];
  int ciX = i % CI;
  int rest = i / CI;
  int coX = rest % a.co[w];
  int k = rest / a.co[w];
  a.dst[w][li] = f2b(a.src[w][coX * a.sco[w] + ciX * a.sci[w] + k * a.sk[w]]);
}

// ======================= enc1 scalar: x(f32,B,1,4096) -> (B,2048,64) bf16, relu ================
__global__ __launch_bounds__(256)
void enc1_bf(const float* __restrict__ x, const float* __restrict__ w1,
             const float* __restrict__ b1, ushort* __restrict__ out) {
  int i = blockIdx.x * 256 + threadIdx.x;    // (n,t): 256*2048
  int t = i & 2047, n = i >> 11;
  const float* xb = x + ((size_t)n << 12);
  int p = 2 * t - 1;
  float x0 = xb[(p + 4096) & 4095];
  float x1 = xb[(p + 4097) & 4095];
  float x2 = xb[(p + 4098) & 4095];
  float x3 = xb[(p + 4099) & 4095];
  uint ow[32];
  #pragma unroll
  for (int c2 = 0; c2 < 32; ++c2) {
    float4 wa = *reinterpret_cast<const float4*>(w1 + 8 * c2);
    float4 wb = *reinterpret_cast<const float4*>(w1 + 8 * c2 + 4);
    float s0 = fmaf(wa.x, x0, fmaf(wa.y, x1, fmaf(wa.z, x2, fmaf(wa.w, x3, b1[2 * c2]))));
    float s1 = fmaf(wb.x, x0, fmaf(wb.y, x1, fmaf(wb.z, x2, fmaf(wb.w, x3, b1[2 * c2 + 1]))));
    ow[c2] = (uint)f2b(fmaxf(s0, 0.0f)) | ((uint)f2b(fmaxf(s1, 0.0f)) << 16);
  }
  uint4* op = reinterpret_cast<uint4*>(out + ((size_t)i << 6));
  #pragma unroll
  for (int q = 0; q < 8; ++q)
    op[q] = uint4{ow[4 * q], ow[4 * q + 1], ow[4 * q + 2], ow[4 * q + 3]};
}

// ======================= MFMA forward conv =======================
// in (B,Tin,CI) bf16 -> out (B,Tout,CO) bf16.  Wb layout: [tap][co][ci] bf16.
// If GATHER: input row t is in[gidx[n*Tin+t]*CI ..] (codebook gather, zero-pad OOB).
template<int CI, int CO, int K, int S, bool CIRC, bool GATHER>
__global__ __launch_bounds__(256)
void conv_mfma(const ushort* __restrict__ in, const ushort* __restrict__ wb,
               const float* __restrict__ bias, const ushort* __restrict__ resid,
               ushort* __restrict__ out, const int* __restrict__ gidx,
               int Tin, int in_relu, int out_relu) {
  constexpr int PAD = (K > 1) ? 1 : 0;
  constexpr int NT = 4;                       // 4 t-tiles = 64 outputs / block
  constexpr int TT = NT * 16;
  constexpr int SPAN = S * (TT - 1) + K;
  constexpr int CIG = CI / 8;                 // 16B granules per row
  constexpr int COT = CO / 16;
  constexpr int WCOT = (COT + 3) / 4;         // co-tiles per wave: 128->2, 64->1, 32->1
  constexpr int WAVES_CO = COT / WCOT;        // 4,4,2
  constexpr int WAVES_T = 4 / WAVES_CO;       // 1,1,2
  constexpr int WTT = NT / WAVES_T;           // 4,4,2
  static_assert(CI % 32 == 0, "");

  __shared__ __align__(16) ushort xs[SPAN * CI];

  const int Tout = Tin / S;
  const int tilesPerB = Tout / TT;
  const int n = blockIdx.x / tilesPerB;
  const int t0 = (blockIdx.x % tilesPerB) * TT;
  const int tid = threadIdx.x;
  const int wid = tid >> 6, lane = tid & 63;
  const int l15 = lane & 15, l4 = lane >> 4;

  // ---- stage X tile ----
  const int t_in0 = S * t0 - PAD;
  const ushort* inb = GATHER ? in : in + (size_t)n * Tin * CI;
  for (int i = tid; i < SPAN * CIG; i += 256) {
    int t = i / CIG, g = i - (i / CIG) * CIG;
    int tg = t_in0 + t;
    uint4 v;
    if (CIRC) {
      tg = (tg < 0) ? tg + Tin : (tg >= Tin ? tg - Tin : tg);
      v = *reinterpret_cast<const uint4*>(inb + (size_t)tg * CI + g * 8);
    } else if (GATHER) {
      if ((unsigned)tg < (unsigned)Tin) {
        int id = gidx[n * Tin + tg];
        v = *reinterpret_cast<const uint4*>(inb + (size_t)id * CI + g * 8);
      } else
        v = uint4{0, 0, 0, 0};
    } else {
      if ((unsigned)tg < (unsigned)Tin)
        v = *reinterpret_cast<const uint4*>(inb + (size_t)tg * CI + g * 8);
      else
        v = uint4{0, 0, 0, 0};
    }
    if (in_relu) {
      ushort* pv = reinterpret_cast<ushort*>(&v);
      #pragma unroll
      for (int e = 0; e < 8; ++e) pv[e] = (pv[e] & 0x8000) ? 0 : pv[e];
    }
    *reinterpret_cast<uint4*>(&xs[t * CI + ((g ^ (t & (CIG - 1))) * 8)]) = v;
  }
  __syncthreads();

  const int wco = wid % WAVES_CO;
  const int wt = wid / WAVES_CO;
  const int co_base = wco * WCOT * 16;
  const int t_base = wt * WTT * 16;

  f32x4 acc[WTT][WCOT] = {};

  for (int cc = 0; cc < CI / 32; ++cc) {
    #pragma unroll
    for (int k = 0; k < K; ++k) {
      bf16x8 bfr[WCOT];
      #pragma unroll
      for (int c = 0; c < WCOT; ++c) {
        const ushort* wp = wb + (size_t)((k * CO + co_base + c * 16 + l15)) * CI + cc * 32 + l4 * 8;
        bfr[c] = __builtin_bit_cast(bf16x8, *reinterpret_cast<const uint4*>(wp));
      }
      #pragma unroll
      for (int tt2 = 0; tt2 < WTT; ++tt2) {
        int trow = S * (t_base + tt2 * 16 + l15) + k;
        int g = cc * 4 + l4;
        bf16x8 afr = __builtin_bit_cast(bf16x8, *reinterpret_cast<const uint4*>(
            &xs[trow * CI + ((g ^ (trow & (CIG - 1))) * 8)]));
        #pragma unroll
        for (int c = 0; c < WCOT; ++c)
          acc[tt2][c] = __builtin_amdgcn_mfma_f32_16x16x32_bf16(afr, bfr[c], acc[tt2][c], 0, 0, 0);
      }
    }
  }

  float bv[WCOT];
  #pragma unroll
  for (int c = 0; c < WCOT; ++c)
    bv[c] = bias ? bias[co_base + c * 16 + l15] : 0.0f;
  ushort* outb = out + (size_t)n * Tout * CO;
  const ushort* resb = resid ? resid + (size_t)n * Tout * CO : nullptr;
  #pragma unroll
  for (int tt2 = 0; tt2 < WTT; ++tt2)
    #pragma unroll
    for (int c = 0; c < WCOT; ++c)
      #pragma unroll
      for (int r = 0; r < 4; ++r) {
        int t = t0 + t_base + tt2 * 16 + 4 * l4 + r;
        int co = co_base + c * 16 + l15;
        float v = acc[tt2][c][r] + bv[c];
        if (resb) v += b2f(resb[(size_t)t * CO + co]);
        if (out_relu) v = fmaxf(v, 0.0f);
        outb[(size_t)t * CO + co] = f2b(v);
      }
}

// ======================= fused residual layer =======================
// out = x + w2 @ relu(conv3(relu(x), w1)) ; x (B,256,128) bf16, circular pad.
// wb1: [tap][32][128], wb2: [128][32]
__global__ __launch_bounds__(256)
void res_mfma(const ushort* __restrict__ in, const ushort* __restrict__ wb1,
              const ushort* __restrict__ wb2, ushort* __restrict__ out) {
  constexpr int CI = 128, CIG = 16;
  constexpr int TT = 64, SPAN = 66, Tin = 256;
  __shared__ __align__(16) ushort xs[SPAN * CI];   // relu'd x
  __shared__ __align__(16) ushort hs[TT][40];      // relu'd h (padded stride)
  const int n = blockIdx.x >> 2;
  const int t0 = (blockIdx.x & 3) * TT;
  const int tid = threadIdx.x;
  const int wid = tid >> 6, lane = tid & 63;
  const int l15 = lane & 15, l4 = lane >> 4;
  const int t_in0 = t0 - 1;
  const ushort* inb = in + (size_t)n * Tin * CI;

  for (int i = tid; i < SPAN * CIG; i += 256) {
    int t = i >> 4, g = i & 15;
    int tg = t_in0 + t;
    tg = (tg < 0) ? tg + Tin : (tg >= Tin ? tg - Tin : tg);
    uint4 v = *reinterpret_cast<const uint4*>(inb + (size_t)tg * CI + g * 8);
    ushort* pv = reinterpret_cast<ushort*>(&v);
    #pragma unroll
    for (int e = 0; e < 8; ++e) pv[e] = (pv[e] & 0x8000) ? 0 : pv[e];
    *reinterpret_cast<uint4*>(&xs[t * CI + ((g ^ (t & 15)) * 8)]) = v;
  }
  __syncthreads();

  // phase 1: wave wid computes h rows [wid*16, wid*16+16) x 32 ch
  {
    f32x4 acc[2] = {};
    for (int cc = 0; cc < 4; ++cc)
      #pragma unroll
      for (int k = 0; k < 3; ++k) {
        bf16x8 bfr[2];
        #pragma unroll
        for (int c = 0; c < 2; ++c)
          bfr[c] = __builtin_bit_cast(bf16x8, *reinterpret_cast<const uint4*>(
              wb1 + (size_t)((k * 32 + c * 16 + l15)) * CI + cc * 32 + l4 * 8));
        int trow = wid * 16 + l15 + k;
        int g = cc * 4 + l4;
        bf16x8 afr = __builtin_bit_cast(bf16x8, *reinterpret_cast<const uint4*>(
            &xs[trow * CI + ((g ^ (trow & 15)) * 8)]));
        acc[0] = __builtin_amdgcn_mfma_f32_16x16x32_bf16(afr, bfr[0], acc[0], 0, 0, 0);
        acc[1] = __builtin_amdgcn_mfma_f32_16x16x32_bf16(afr, bfr[1], acc[1], 0, 0, 0);
      }
    #pragma unroll
    for (int c = 0; c < 2; ++c)
      #pragma unroll
      for (int r = 0; r < 4; ++r) {
        float v = acc[c][r];
        hs[wid * 16 + l4 * 4 + r][c * 16 + l15] = (v > 0.0f) ? f2b(v) : (ushort)0;
      }
  }
  __syncthreads();

  // phase 2: 1x1 conv 32->128, K=32 single MFMA per co-tile; + residual from global
  {
    bf16x8 afr = *reinterpret_cast<const bf16x8*>(&hs[wid * 16 + l15][l4 * 8]);
    f32x4 acc[8];
    #pragma unroll
    for (int c = 0; c < 8; ++c) {
      bf16x8 bfr = __builtin_bit_cast(bf16x8, *reinterpret_cast<const uint4*>(
          wb2 + (size_t)(c * 16 + l15) * 32 + l4 * 8));
      f32x4 z = {};
      acc[c] = __builtin_amdgcn_mfma_f32_16x16x32_bf16(afr, bfr, z, 0, 0, 0);
    }
    ushort* outb = out + (size_t)n * Tin * CI;
    #pragma unroll
    for (int c = 0; c < 8; ++c)
      #pragma unroll
      for (int r = 0; r < 4; ++r) {
        int t = t0 + wid * 16 + l4 * 4 + r;
        int co = c * 16 + l15;
        float v = acc[c][r] + b2f(inb[(size_t)t * CI + co]);
        outb[(size_t)t * CI + co] = f2b(v);
      }
  }
}

// ======================= MFMA transposed conv k=4 s=2 p=1 (CI=128) =======================
template<int CO>
__global__ __launch_bounds__(256)
void convt_mfma(const ushort* __restrict__ in, const ushort* __restrict__ wb,
                const float* __restrict__ bias, ushort* __restrict__ out,
                int Tin, int in_relu, int out_relu) {
  constexpr int CI = 128, CIG = 16;
  constexpr int NT = 4, TT = 64;
  constexpr int SPAN = TT + 2;
  constexpr int COT = CO / 16;
  constexpr int WCOT = (COT + 3) / 4;
  constexpr int WAVES_CO = COT / WCOT;
  constexpr int WTT = NT;

  __shared__ __align__(16) ushort xs[SPAN * CI];

  const int Tout = 2 * Tin;
  const int tilesPerB = Tin / TT;
  const int n = blockIdx.x / tilesPerB;
  const int tp0 = (blockIdx.x % tilesPerB) * TT;
  const int tid = threadIdx.x;
  const int wid = tid >> 6, lane = tid & 63;
  const int l15 = lane & 15, l4 = lane >> 4;

  const int t_in0 = tp0 - 1;
  const ushort* inb = in + (size_t)n * Tin * CI;
  for (int i = tid; i < SPAN * CIG; i += 256) {
    int t = i >> 4, g = i & 15;
    int tg = t_in0 + t;
    uint4 v;
    if ((unsigned)tg < (unsigned)Tin)
      v = *reinterpret_cast<const uint4*>(inb + (size_t)tg * CI + g * 8);
    else
      v = uint4{0, 0, 0, 0};
    if (in_relu) {
      ushort* pv = reinterpret_cast<ushort*>(&v);
      #pragma unroll
      for (int e = 0; e < 8; ++e) pv[e] = (pv[e] & 0x8000) ? 0 : pv[e];
    }
    *reinterpret_cast<uint4*>(&xs[t * CI + ((g ^ (t & 15)) * 8)]) = v;
  }
  __syncthreads();

  const int wco = wid % WAVES_CO;
  const int co_base = wco * WCOT * 16;

  f32x4 accE[WTT][WCOT] = {};
  f32x4 accO[WTT][WCOT] = {};

  for (int cc = 0; cc < 4; ++cc) {
    bf16x8 bk[4][WCOT];
    #pragma unroll
    for (int k = 0; k < 4; ++k)
      #pragma unroll
      for (int c = 0; c < WCOT; ++c) {
        const ushort* wp = wb + (size_t)((k * CO + co_base + c * 16 + l15)) * CI + cc * 32 + l4 * 8;
        bk[k][c] = __builtin_bit_cast(bf16x8, *reinterpret_cast<const uint4*>(wp));
      }
    #pragma unroll
    for (int tt2 = 0; tt2 < WTT; ++tt2) {
      int lt = tt2 * 16 + l15 + 1;
      int g = cc * 4 + l4;
      bf16x8 a0 = __builtin_bit_cast(bf16x8, *reinterpret_cast<const uint4*>(
          &xs[lt * CI + ((g ^ (lt & 15)) * 8)]));
      bf16x8 am = __builtin_bit_cast(bf16x8, *reinterpret_cast<const uint4*>(
          &xs[(lt - 1) * CI + ((g ^ ((lt - 1) & 15)) * 8)]));
      bf16x8 ap = __builtin_bit_cast(bf16x8, *reinterpret_cast<const uint4*>(
          &xs[(lt + 1) * CI + ((g ^ ((lt + 1) & 15)) * 8)]));
      #pragma unroll
      for (int c = 0; c < WCOT; ++c) {
        accE[tt2][c] = __builtin_amdgcn_mfma_f32_16x16x32_bf16(a0, bk[1][c], accE[tt2][c], 0, 0, 0);
        accE[tt2][c] = __builtin_amdgcn_mfma_f32_16x16x32_bf16(am, bk[3][c], accE[tt2][c], 0, 0, 0);
        accO[tt2][c] = __builtin_amdgcn_mfma_f32_16x16x32_bf16(ap, bk[0][c], accO[tt2][c], 0, 0, 0);
        accO[tt2][c] = __builtin_amdgcn_mfma_f32_16x16x32_bf16(a0, bk[2][c], accO[tt2][c], 0, 0, 0);
      }
    }
  }

  float bv[WCOT];
  #pragma unroll
  for (int c = 0; c < WCOT; ++c) bv[c] = bias[co_base + c * 16 + l15];
  ushort* outb = out + (size_t)n * Tout * CO;
  #pragma unroll
  for (int tt2 = 0; tt2 < WTT; ++tt2)
    #pragma unroll
    for (int c = 0; c < WCOT; ++c)
      #pragma unroll
      for (int r = 0; r < 4; ++r) {
        int tp = tp0 + tt2 * 16 + 4 * l4 + r;
        int co = co_base + c * 16 + l15;
        float vE = accE[tt2][c][r] + bv[c];
        float vO = accO[tt2][c][r] + bv[c];
        if (out_relu) { vE = fmaxf(vE, 0.0f); vO = fmaxf(vO, 0.0f); }
        outb[(size_t)(2 * tp) * CO + co] = f2b(vE);
        outb[(size_t)(2 * tp + 1) * CO + co] = f2b(vO);
      }
}

// ======================= ct3 scalar: (B,2048,64) bf16 -> (B,4096) f32 =======================
__global__ __launch_bounds__(256)
void ct3_bf(const ushort* __restrict__ in, const float* __restrict__ w3,
            const float* __restrict__ b3, float* __restrict__ out) {
  constexpr int SPAN = 130;
  __shared__ __align__(16) ushort ys[SPAN * 64];
  const int n = blockIdx.x >> 4;
  const int ot0 = (blockIdx.x & 15) << 8;
  const int tid = threadIdx.x;
  const int t_in0 = (ot0 >> 1) - 1;
  const ushort* inb = in + (size_t)n * 2048 * 64;
  for (int i = tid; i < SPAN * 8; i += 256) {
    int t = i >> 3, g = i & 7;
    int tg = t_in0 + t;
    uint4 v;
    if ((unsigned)tg < 2048u)
      v = *reinterpret_cast<const uint4*>(inb + (size_t)tg * 64 + g * 8);
    else
      v = uint4{0, 0, 0, 0};
    *reinterpret_cast<uint4*>(&ys[t * 64 + ((g ^ (t & 7)) * 8)]) = v;
  }
  __syncthreads();
  const int ot = ot0 + tid;
  const int odd = ot & 1;
  const int it_a = odd ? ((ot + 1) >> 1) : (ot >> 1);
  const int it_b = odd ? ((ot - 1) >> 1) : (ot / 2 - 1);
  const int ka = odd ? 0 : 1;
  const int kb = odd ? 2 : 3;
  const int lt_a = it_a - t_in0, lt_b = it_b - t_in0;
  float s = b3[0];
  #pragma unroll
  for (int g = 0; g < 8; ++g) {
    uint4 va = *reinterpret_cast<const uint4*>(&ys[lt_a * 64 + ((g ^ (lt_a & 7)) * 8)]);
    uint4 vb = *reinterpret_cast<const uint4*>(&ys[lt_b * 64 + ((g ^ (lt_b & 7)) * 8)]);
    const ushort* pa = reinterpret_cast<const ushort*>(&va);
    const ushort* pb = reinterpret_cast<const ushort*>(&vb);
    #pragma unroll
    for (int e = 0; e < 8; ++e) {
      int ci = g * 8 + e;
      s = fmaf(w3[ci * 4 + ka], b2f(pa[e]), s);
      s = fmaf(w3[ci * 4 + kb], b2f(pb[e]), s);
    }
  }
  out[(size_t)n * 4096 + ot] = s;
}

// ======================= VQ =======================
__global__ void ee_kernel(const float* __restrict__ emb, float* __restrict__ ee) {
  int c = blockIdx.x * 256 + threadIdx.x;
  if (c >= 512) return;
  float s = 0.0f;
  #pragma unroll
  for (int d = 0; d < 64; ++d) { float v = emb[c * 64 + d]; s = fmaf(v, v, s); }
  ee[c] = s;
}

// MFMA VQ, RT=4 row-tiles per wave (256 rows/block, grid 256).
__global__ __launch_bounds__(256)
void vq_mfma(const ushort* __restrict__ zt, const ushort* __restrict__ embb,
             const float* __restrict__ ee, int* __restrict__ idx,
             int* __restrict__ hist, float* __restrict__ loss_accum) {
  __shared__ __align__(16) ushort es[512 * 64];
  __shared__ float eel[512];
  __shared__ int lhist[512];
  const int tid = threadIdx.x;
  const int wid = tid >> 6, lane = tid & 63;
  const int l15 = lane & 15, l4 = lane >> 4;

  for (int i = tid; i < 512 * 8; i += 256) {
    int c = i >> 3, g = i & 7;
    reinterpret_cast<uint4*>(es)[c * 8 + (g ^ (c & 7))] =
        reinterpret_cast<const uint4*>(embb)[i];
  }
  for (int i = tid; i < 512; i += 256) { eel[i] = ee[i]; lhist[i] = 0; }
  __syncthreads();

  const int rb = blockIdx.x * 256 + wid * 64;
  bf16x8 bz[4][2];
  float zz[4], best[4];
  int bi[4];
  #pragma unroll
  for (int rt = 0; rt < 4; ++rt) {
    const int r = rb + rt * 16 + l15;
    uint4 v0 = *reinterpret_cast<const uint4*>(zt + (size_t)r * 64 + l4 * 8);
    uint4 v1 = *reinterpret_cast<const uint4*>(zt + (size_t)r * 64 + 32 + l4 * 8);
    bz[rt][0] = __builtin_bit_cast(bf16x8, v0);
    bz[rt][1] = __builtin_bit_cast(bf16x8, v1);
    float s = 0.0f;
    const ushort* p0 = reinterpret_cast<const ushort*>(&v0);
    const ushort* p1 = reinterpret_cast<const ushort*>(&v1);
    #pragma unroll
    for (int e = 0; e < 8; ++e) {
      float f0 = b2f(p0[e]), f1 = b2f(p1[e]);
      s = fmaf(f0, f0, fmaf(f1, f1, s));
    }
    s += __shfl_xor(s, 16);
    s += __shfl_xor(s, 32);
    zz[rt] = s;
    best[rt] = 3.4e38f;
    bi[rt] = 0;
  }

  for (int ct = 0; ct < 32; ++ct) {
    const int c = ct * 16 + l15;
    bf16x8 a0 = __builtin_bit_cast(bf16x8, reinterpret_cast<const uint4*>(es)[
        c * 8 + (l4 ^ (c & 7))]);
    bf16x8 a1 = __builtin_bit_cast(bf16x8, reinterpret_cast<const uint4*>(es)[
        c * 8 + ((4 | l4) ^ (c & 7))]);
    #pragma unroll
    for (int rt = 0; rt < 4; ++rt) {
      f32x4 acc = {};
      acc = __builtin_amdgcn_mfma_f32_16x16x32_bf16(a0, bz[rt][0], acc, 0, 0, 0);
      acc = __builtin_amdgcn_mfma_f32_16x16x32_bf16(a1, bz[rt][1], acc, 0, 0, 0);
      #pragma unroll
      for (int rr = 0; rr < 4; ++rr) {
        int code = ct * 16 + l4 * 4 + rr;
        float d = eel[code] - 2.0f * acc[rr];
        if (d < best[rt] || (d == best[rt] && code < bi[rt])) { best[rt] = d; bi[rt] = code; }
      }
    }
  }
  float vsum = 0.0f;
  #pragma unroll
  for (int rt = 0; rt < 4; ++rt) {
    #pragma unroll
    for (int m = 16; m <= 32; m <<= 1) {
      float ob = __shfl_xor(best[rt], m);
      int oi = __shfl_xor(bi[rt], m);
      if (ob < best[rt] || (ob == best[rt] && oi < bi[rt])) { best[rt] = ob; bi[rt] = oi; }
    }
    if (l4 == 0) {
      idx[rb + rt * 16 + l15] = bi[rt];
      atomicAdd(&lhist[bi[rt]], 1);
      vsum += zz[rt] + best[rt];
    }
  }
  #pragma unroll
  for (int m = 1; m < 64; m <<= 1) vsum += __shfl_xor(vsum, m);
  if (lane == 0) atomicAdd(loss_accum, vsum);
  __syncthreads();
  for (int i = tid; i < 512; i += 256)
    if (lhist[i]) atomicAdd(&hist[i], lhist[i]);
}

__global__ __launch_bounds__(512)
void finalize(const int* __restrict__ hist, const float* __restrict__ loss_accum,
              float* __restrict__ out) {
  __shared__ float red[8];
  int tid = threadIdx.x;
  float avg = (float)hist[tid] * (1.0f / 65536.0f);
  float v = avg * logf(avg + 1e-10f);
  for (int off = 32; off > 0; off >>= 1) v += __shfl_down(v, off);
  if ((tid & 63) == 0) red[tid >> 6] = v;
  __syncthreads();
  if (tid == 0) {
    float s = 0.0f;
    for (int i = 0; i < 8; ++i) s += red[i];
    out[1048577] = expf(-s);
    out[0] = 1.25f * loss_accum[0] * (1.0f / (65536.0f * 64.0f));
  }
}

// ======================= launcher =======================
extern "C" void kernel_launch(void* const* d_in, const int* in_sizes, int n_in,
                              void* d_out, int out_size, void* d_ws, size_t ws_size,
                              hipStream_t stream) {
  (void)in_sizes; (void)n_in; (void)out_size; (void)ws_size;
  const float* x    = (const float*)d_in[0];
  const float* c1w  = (const float*)d_in[1];
  const float* c1b  = (const float*)d_in[2];
  const float* c2w  = (const float*)d_in[3];
  const float* c2b  = (const float*)d_in[4];
  const float* c3w  = (const float*)d_in[5];
  const float* c3b  = (const float*)d_in[6];
  const float* c4w  = (const float*)d_in[7];
  const float* c4b  = (const float*)d_in[8];
  const float* cfw  = (const float*)d_in[9];
  const float* cfb  = (const float*)d_in[10];
  const float* erw1 = (const float*)d_in[11];
  const float* erw2 = (const float*)d_in[12];
  const float* pqw  = (const float*)d_in[13];
  const float* pqb  = (const float*)d_in[14];
  const float* emb  = (const float*)d_in[15];
  const float* diw  = (const float*)d_in[16];
  const float* dib  = (const float*)d_in[17];
  const float* drw1 = (const float*)d_in[18];
  const float* drw2 = (const float*)d_in[19];
  const float* t0w  = (const float*)d_in[20];
  const float* t0b  = (const float*)d_in[21];
  const float* t1w  = (const float*)d_in[22];
  const float* t1b  = (const float*)d_in[23];
  const float* t2w  = (const float*)d_in[24];
  const float* t2b  = (const float*)d_in[25];
  const float* t3w  = (const float*)d_in[26];
  const float* t3b  = (const float*)d_in[27];

  char* wsb = (char*)d_ws;
  ushort* R0 = (ushort*)wsb;                           // e1 ; later ct1-out
  ushort* R1 = (ushort*)(wsb + 67108864);              // e2 ; later ct2-out
  ushort* R2 = (ushort*)(wsb + 134217728);             // e3 ; later ct0-out
  ushort* R3 = (ushort*)(wsb + 0);                     // e4 / dec ping
  ushort* R4 = (ushort*)(wsb + 16777216);              // cf / dec pong
  ushort* R6 = (ushort*)(wsb + 37748736);              // zt (BT,64)
  // weights (bf16) region:
  ushort* WPu = (ushort*)(wsb + 167772160);
  ushort* wb_e2 = WPu + 0;
  ushort* wb_e3 = WPu + 32768;
  ushort* wb_e4 = WPu + 98304;
  ushort* wb_cf = WPu + 163840;
  ushort* wb_r1a = WPu + 212992;
  ushort* wb_r1b = WPu + 225280;
  ushort* wb_r2a = WPu + 237568;
  ushort* wb_r2b = WPu + 241664;
  ushort* wb_pq = WPu + 245760;
  ushort* wb_di = WPu + 253952;
  ushort* wb_d1a = WPu + 278528;
  ushort* wb_d1b = WPu + 290816;
  ushort* wb_d2a = WPu + 303104;
  ushort* wb_d2b = WPu + 307200;
  ushort* wb_t0 = WPu + 311296;
  ushort* wb_t1 = WPu + 376832;
  ushort* wb_t2 = WPu + 442368;
  ushort* wb_emb = WPu + 475136;
  char* fp = wsb + 167772160 + 1048576;
  float* eeb   = (float*)fp;
  int*   idxb  = (int*)(fp + 2048);
  int*   histb = (int*)(fp + 2048 + 262144);
  float* lossb = (float*)(fp + 2048 + 262144 + 2048);
  float* outp  = (float*)d_out;

  hipMemsetAsync(histb, 0, 512 * sizeof(int), stream);
  hipMemsetAsync(lossb, 0, sizeof(float), stream);

  // ---- weight prep ----
  PrepArgs pa{};
  int nw = 0, total = 0;
  auto addw = [&](const float* src, ushort* dst, int CO, int CI, int K,
                  int sco, int sci, int sk) {
    pa.tot[nw] = K * CO * CI; pa.src[nw] = src; pa.dst[nw] = dst;
    pa.ci[nw] = CI; pa.co[nw] = CO; pa.sco[nw] = sco; pa.sci[nw] = sci; pa.sk[nw] = sk;
    total += pa.tot[nw]; ++nw;
  };
  addw(c2w, wb_e2, 128, 64, 4, 256, 4, 1);
  addw(c3w, wb_e3, 128, 128, 4, 512, 4, 1);
  addw(c4w, wb_e4, 128, 128, 4, 512, 4, 1);
  addw(cfw, wb_cf, 128, 128, 3, 384, 3, 1);
  addw(erw1, wb_r1a, 32, 128, 3, 384, 3, 1);
  addw(erw1 + 12288, wb_r1b, 32, 128, 3, 384, 3, 1);
  addw(erw2, wb_r2a, 128, 32, 1, 32, 1, 1);
  addw(erw2 + 4096, wb_r2b, 128, 32, 1, 32, 1, 1);
  addw(pqw, wb_pq, 64, 128, 1, 128, 1, 1);
  addw(diw, wb_di, 128, 64, 3, 192, 3, 1);
  addw(drw1, wb_d1a, 32, 128, 3, 384, 3, 1);
  addw(drw1 + 12288, wb_d1b, 32, 128, 3, 384, 3, 1);
  addw(drw2, wb_d2a, 128, 32, 1, 32, 1, 1);
  addw(drw2 + 4096, wb_d2b, 128, 32, 1, 32, 1, 1);
  addw(t0w, wb_t0, 128, 128, 4, 4, 512, 1);
  addw(t1w, wb_t1, 128, 128, 4, 4, 512, 1);
  addw(t2w, wb_t2, 64, 128, 4, 4, 256, 1);
  addw(emb, wb_emb, 512, 64, 1, 64, 1, 1);
  pa.nw = nw;
  prep_all<<<(total + 255) / 256, 256, 0, stream>>>(pa, total);
  ee_kernel<<<2, 256, 0, stream>>>(emb, eeb);

  // ---- encoder ----
  enc1_bf<<<2048, 256, 0, stream>>>(x, c1w, c1b, R0);
  conv_mfma<64, 128, 4, 2, true, false><<<4096, 256, 0, stream>>>(R0, wb_e2, c2b, nullptr, R1, nullptr, 2048, 0, 1);
  conv_mfma<128, 128, 4, 2, true, false><<<2048, 256, 0, stream>>>(R1, wb_e3, c3b, nullptr, R2, nullptr, 1024, 0, 1);
  conv_mfma<128, 128, 4, 2, true, false><<<1024, 256, 0, stream>>>(R2, wb_e4, c4b, nullptr, R3, nullptr, 512, 0, 1);
  conv_mfma<128, 128, 3, 1, true, false><<<1024, 256, 0, stream>>>(R3, wb_cf, cfb, nullptr, R4, nullptr, 256, 0, 0);
  // encoder residual stack (fused per layer)
  res_mfma<<<1024, 256, 0, stream>>>(R4, wb_r1a, wb_r2a, R3);
  res_mfma<<<1024, 256, 0, stream>>>(R3, wb_r1b, wb_r2b, R4);
  // pre-VQ 1x1 (+ final res relu via in_relu) -> zt (BT,64)
  conv_mfma<128, 64, 1, 1, false, false><<<1024, 256, 0, stream>>>(R4, wb_pq, pqb, nullptr, R6, nullptr, 256, 1, 0);
  // ---- VQ ----
  vq_mfma<<<256, 256, 0, stream>>>(R6, wb_emb, eeb, idxb, histb, lossb);
  finalize<<<1, 512, 0, stream>>>(histb, lossb, outp);
  // ---- decoder (dec_init gathers q directly from codebook via idx) ----
  conv_mfma<64, 128, 3, 1, false, true><<<1024, 256, 0, stream>>>(wb_emb, wb_di, dib, nullptr, R3, idxb, 256, 0, 0);
  res_mfma<<<1024, 256, 0, stream>>>(R3, wb_d1a, wb_d2a, R4);
  res_mfma<<<1024, 256, 0, stream>>>(R4, wb_d1b, wb_d2b, R3);
  convt_mfma<128><<<1024, 256, 0, stream>>>(R3, wb_t0, t0b, R2, 256, 1, 1);
  convt_mfma<128><<<2048, 256, 0, stream>>>(R2, wb_t1, t1b, R0, 512, 0, 1);
  convt_mfma<64><<<4096, 256, 0, stream>>>(R0, wb_t2, t2b, R1, 1024, 0, 1);
  ct3_bf<<<4096, 256, 0, stream>>>(R1, t3w, t3b, outp + 1);
}